// Round 1
// baseline (1089.399 us; speedup 1.0000x reference)
//
#include <hip/hip_runtime.h>

#define NN 100000

// ---------------- CSR build ----------------
__global__ void k_count(const int* __restrict__ dst, int* __restrict__ deg, int E) {
  int e = blockIdx.x * blockDim.x + threadIdx.x;
  if (e < E) atomicAdd(&deg[dst[e]], 1);
}

#define SCAN_T 256
#define SCAN_E 8
#define SCAN_CHUNK (SCAN_T * SCAN_E)

__global__ void k_scan1(const int* __restrict__ deg, int* __restrict__ outp,
                        int* __restrict__ bsum, int n) {
  __shared__ int sh[SCAN_T];
  int t = threadIdx.x;
  int base = blockIdx.x * SCAN_CHUNK + t * SCAN_E;
  int v[SCAN_E];
  int s = 0;
#pragma unroll
  for (int i = 0; i < SCAN_E; ++i) {
    int idx = base + i;
    int d = (idx < n) ? deg[idx] : 0;
    v[i] = s;
    s += d;
  }
  sh[t] = s;
  __syncthreads();
  for (int off = 1; off < SCAN_T; off <<= 1) {
    int add = (t >= off) ? sh[t - off] : 0;
    __syncthreads();
    sh[t] += add;
    __syncthreads();
  }
  int prefix = (t > 0) ? sh[t - 1] : 0;
#pragma unroll
  for (int i = 0; i < SCAN_E; ++i) {
    int idx = base + i;
    if (idx < n) outp[idx] = prefix + v[i];
  }
  if (t == SCAN_T - 1) bsum[blockIdx.x] = sh[t];
}

__global__ void k_scan2(int* bsum, int nb) {
  if (threadIdx.x == 0) {
    int s = 0;
    for (int i = 0; i < nb; ++i) {
      int d = bsum[i];
      bsum[i] = s;
      s += d;
    }
  }
}

__global__ void k_scan3(int* __restrict__ rp, const int* __restrict__ bsum,
                        int* __restrict__ cur, int n, int E) {
  int i = blockIdx.x * blockDim.x + threadIdx.x;
  if (i < n) {
    int v = rp[i] + bsum[i / SCAN_CHUNK];
    rp[i] = v;
    cur[i] = v;
  }
  if (i == 0) rp[n] = E;
}

__global__ void k_fill(const int* __restrict__ src, const int* __restrict__ dst,
                       int* __restrict__ cur, int* __restrict__ col, int E) {
  int e = blockIdx.x * blockDim.x + threadIdx.x;
  if (e < E) {
    int p = atomicAdd(&cur[dst[e]], 1);
    col[p] = src[e];
  }
}

// ---------------- mean aggregation (wave per node) ----------------
template <int F>
__global__ void k_agg(const float* __restrict__ x, const int* __restrict__ rp,
                      const int* __restrict__ col, float* __restrict__ out, int n) {
  int w = (blockIdx.x * blockDim.x + threadIdx.x) >> 6;
  int lane = threadIdx.x & 63;
  if (w >= n) return;
  int beg = rp[w], end = rp[w + 1];
  float s0 = 0.f, s1 = 0.f;
  for (int j = beg; j < end; ++j) {
    int c = col[j];
    const float* p = x + (size_t)c * F;
    s0 += p[lane];
    if (F == 128) s1 += p[64 + lane];
  }
  int d = end - beg;
  float inv = 1.0f / (float)(d > 0 ? d : 1);
  float* o = out + (size_t)w * F;
  o[lane] = s0 * inv;
  if (F == 128) o[64 + lane] = s1 * inv;
}

// ---------------- fused dual GEMM: out = act(A@Wa^T [+ B@Wb^T] [+ bias] [+ addc]) ----------------
// W is (H, K) row-major. BM=128 rows/block, BN=H cols (H<=128). 8x8 micro-tile.
template <int K, int H, bool RELU, bool DUAL, bool ADDC>
__global__ __launch_bounds__(256, 2) void k_gemm(
    const float* __restrict__ A, const float* __restrict__ Wa,
    const float* __restrict__ B, const float* __restrict__ Wb,
    const float* __restrict__ bias, const float* __restrict__ addc,
    float* __restrict__ out, int n) {
  constexpr int BM = 128;
  constexpr int KS = 16;
  constexpr int LDA = BM + 4;  // pad -> 2-way (free) staging conflicts
  constexpr int LDW = H + 4;
  __shared__ float A_s[KS][LDA];
  __shared__ float W_s[KS][LDW];
  const int tx = threadIdx.x;  // [0, H/8)
  const int ty = threadIdx.y;  // [0, 16)
  const int tid = ty * blockDim.x + tx;
  const int nthr = blockDim.x * blockDim.y;
  const int blockRow = blockIdx.x * BM;

  float acc[8][8];
#pragma unroll
  for (int i = 0; i < 8; ++i)
#pragma unroll
    for (int j = 0; j < 8; ++j) acc[i][j] = 0.f;

#pragma unroll
  for (int phase = 0; phase < (DUAL ? 2 : 1); ++phase) {
    const float* __restrict__ Ap = phase ? B : A;
    const float* __restrict__ Wp = phase ? Wb : Wa;
    for (int k0 = 0; k0 < K; k0 += KS) {
      __syncthreads();
      // stage A tile (transposed into LDS: A_s[k][row])
      for (int idx = tid; idx < BM * (KS / 4); idx += nthr) {
        int r = idx >> 2, kv = (idx & 3) * 4;
        int row = blockRow + r;
        float4 v;
        if (row < n)
          v = *(const float4*)&Ap[(size_t)row * K + k0 + kv];
        else
          v = make_float4(0.f, 0.f, 0.f, 0.f);
        A_s[kv + 0][r] = v.x;
        A_s[kv + 1][r] = v.y;
        A_s[kv + 2][r] = v.z;
        A_s[kv + 3][r] = v.w;
      }
      // stage W tile (transposed: W_s[k][col])
      for (int idx = tid; idx < H * (KS / 4); idx += nthr) {
        int c = idx >> 2, kv = (idx & 3) * 4;
        float4 v = *(const float4*)&Wp[(size_t)c * K + k0 + kv];
        W_s[kv + 0][c] = v.x;
        W_s[kv + 1][c] = v.y;
        W_s[kv + 2][c] = v.z;
        W_s[kv + 3][c] = v.w;
      }
      __syncthreads();
#pragma unroll
      for (int kk = 0; kk < KS; ++kk) {
        float4 a0 = *(const float4*)&A_s[kk][ty * 8];
        float4 a1 = *(const float4*)&A_s[kk][ty * 8 + 4];
        float4 w0 = *(const float4*)&W_s[kk][tx * 8];
        float4 w1 = *(const float4*)&W_s[kk][tx * 8 + 4];
        float a[8] = {a0.x, a0.y, a0.z, a0.w, a1.x, a1.y, a1.z, a1.w};
        float w[8] = {w0.x, w0.y, w0.z, w0.w, w1.x, w1.y, w1.z, w1.w};
#pragma unroll
        for (int i = 0; i < 8; ++i)
#pragma unroll
          for (int j = 0; j < 8; ++j) acc[i][j] = fmaf(a[i], w[j], acc[i][j]);
      }
    }
  }
  // epilogue
#pragma unroll
  for (int i = 0; i < 8; ++i) {
    int row = blockRow + ty * 8 + i;
    if (row >= n) continue;
    size_t base = (size_t)row * H + tx * 8;
    float vals[8];
#pragma unroll
    for (int j = 0; j < 8; ++j) {
      int c = tx * 8 + j;
      float v = acc[i][j];
      if (bias) v += bias[c];
      vals[j] = v;
    }
    if (ADDC) {
      float4 c0 = *(const float4*)&addc[base];
      float4 c1 = *(const float4*)&addc[base + 4];
      vals[0] += c0.x; vals[1] += c0.y; vals[2] += c0.z; vals[3] += c0.w;
      vals[4] += c1.x; vals[5] += c1.y; vals[6] += c1.z; vals[7] += c1.w;
    }
    if (RELU) {
#pragma unroll
      for (int j = 0; j < 8; ++j) vals[j] = fmaxf(vals[j], 0.f);
    }
    *(float4*)&out[base] = make_float4(vals[0], vals[1], vals[2], vals[3]);
    *(float4*)&out[base + 4] = make_float4(vals[4], vals[5], vals[6], vals[7]);
  }
}

// ---------------- edge dot (wave per sampled edge) ----------------
__global__ void k_dot(const float* __restrict__ emb, const int* __restrict__ ea,
                      const int* __restrict__ eb, float* __restrict__ out, int ne) {
  int w = (blockIdx.x * blockDim.x + threadIdx.x) >> 6;
  int lane = threadIdx.x & 63;
  if (w >= ne) return;
  const float* pa = emb + (size_t)ea[w] * 64;
  const float* pb = emb + (size_t)eb[w] * 64;
  float v = pa[lane] * pb[lane];
#pragma unroll
  for (int off = 32; off > 0; off >>= 1) v += __shfl_down(v, off, 64);
  if (lane == 0) out[w] = v;
}

extern "C" void kernel_launch(void* const* d_in, const int* in_sizes, int n_in,
                              void* d_out, int out_size, void* d_ws, size_t ws_size,
                              hipStream_t stream) {
  const float* x = (const float*)d_in[0];
  const int* ei = (const int*)d_in[1];
  const int* es = (const int*)d_in[2];
  const float* Wl0 = (const float*)d_in[3];
  const float* Wr0 = (const float*)d_in[4];
  const float* b0 = (const float*)d_in[5];
  const float* Wl1 = (const float*)d_in[6];
  const float* Wr1 = (const float*)d_in[7];
  const float* b1 = (const float*)d_in[8];
  const float* Wl2 = (const float*)d_in[9];
  const float* Wr2 = (const float*)d_in[10];
  const float* b2 = (const float*)d_in[11];
  const float* Wd1 = (const float*)d_in[12];
  const float* bd1 = (const float*)d_in[13];
  const float* Wd2 = (const float*)d_in[14];
  const float* bd2 = (const float*)d_in[15];

  const int E = in_sizes[1] / 2;
  const int ES = in_sizes[2] / 2;
  const int* srcv = ei;
  const int* dstv = ei + E;
  const int* ea = es;
  const int* eb = es + ES;

  char* wp = (char*)d_ws;
  auto alloc = [&](size_t bytes) {
    char* p = wp;
    wp += (bytes + 511) & ~(size_t)511;
    return p;
  };
  int* row_ptr = (int*)alloc((NN + 1) * sizeof(int));
  int* cursor = (int*)alloc((size_t)NN * sizeof(int));
  int* colv = (int*)alloc((size_t)E * sizeof(int));
  int* bsum = (int*)alloc(256 * sizeof(int));
  float* bufA = (float*)alloc((size_t)NN * 128 * sizeof(float));
  float* bufH1 = (float*)alloc((size_t)NN * 128 * sizeof(float));
  float* bufH2 = (float*)alloc((size_t)NN * 128 * sizeof(float));

  float* out_emb = (float*)d_out;
  float* out_rec = out_emb + (size_t)NN * 64;
  float* out_sc = out_rec + (size_t)NN * 64;

  // --- CSR build (dst-sorted src list) ---
  hipMemsetAsync(cursor, 0, (size_t)NN * sizeof(int), stream);
  k_count<<<(E + 255) / 256, 256, 0, stream>>>(dstv, cursor, E);
  int nb = (NN + SCAN_CHUNK - 1) / SCAN_CHUNK;
  k_scan1<<<nb, SCAN_T, 0, stream>>>(cursor, row_ptr, bsum, NN);
  k_scan2<<<1, 64, 0, stream>>>(bsum, nb);
  k_scan3<<<(NN + 255) / 256, 256, 0, stream>>>(row_ptr, bsum, cursor, NN, E);
  k_fill<<<(E + 255) / 256, 256, 0, stream>>>(srcv, dstv, cursor, colv, E);

  const int aggGrid = (NN + 3) / 4;  // 4 waves/block
  dim3 g128((NN + 127) / 128);
  dim3 b16x16(16, 16), b8x16(8, 16);

  // layer 0: agg0 = mean(x); h1 = relu(agg0@Wl0^T + x@Wr0^T + b0)
  k_agg<64><<<aggGrid, 256, 0, stream>>>(x, row_ptr, colv, bufA, NN);
  k_gemm<64, 128, true, true, false><<<g128, b16x16, 0, stream>>>(bufA, Wl0, x, Wr0, b0, nullptr, bufH1, NN);
  // layer 1
  k_agg<128><<<aggGrid, 256, 0, stream>>>(bufH1, row_ptr, colv, bufA, NN);
  k_gemm<128, 128, true, true, false><<<g128, b16x16, 0, stream>>>(bufA, Wl1, bufH1, Wr1, b1, nullptr, bufH2, NN);
  // layer 2 (aggregate after projecting to 64: mean(h2)@Wl2^T == mean(h2@Wl2^T))
  k_gemm<128, 64, false, false, false><<<g128, b8x16, 0, stream>>>(bufH2, Wl2, nullptr, nullptr, nullptr, nullptr, bufA, NN);
  k_agg<64><<<aggGrid, 256, 0, stream>>>(bufA, row_ptr, colv, bufH1, NN);
  k_gemm<128, 64, false, false, true><<<g128, b8x16, 0, stream>>>(bufH2, Wr2, nullptr, nullptr, b2, bufH1, out_emb, NN);
  // decoder
  k_gemm<64, 128, true, false, false><<<g128, b16x16, 0, stream>>>(out_emb, Wd1, nullptr, nullptr, bd1, nullptr, bufH2, NN);
  k_gemm<128, 64, false, false, false><<<g128, b8x16, 0, stream>>>(bufH2, Wd2, nullptr, nullptr, bd2, nullptr, out_rec, NN);
  // edge scores
  k_dot<<<(ES + 3) / 4, 256, 0, stream>>>(out_emb, ea, eb, out_sc, ES);
}

// Round 2
// 585.649 us; speedup vs baseline: 1.8602x; 1.8602x over previous
//
#include <hip/hip_runtime.h>

#define NN 100000
typedef unsigned int uint;
typedef unsigned short ushort;

using f32x4 = __attribute__((ext_vector_type(4))) float;
using s16x8 = __attribute__((ext_vector_type(8))) short;

__device__ inline ushort f32_to_bf16(float f) {
  uint u = __float_as_uint(f);
  uint r = (u + 0x7FFFu + ((u >> 16) & 1u)) >> 16;
  return (ushort)r;
}
__device__ inline float bf16_to_f32(ushort h) {
  return __uint_as_float(((uint)h) << 16);
}

// ---------------- CSR build ----------------
__global__ void k_count(const int* __restrict__ dst, int* __restrict__ deg, int E) {
  int e = blockIdx.x * blockDim.x + threadIdx.x;
  if (e < E) atomicAdd(&deg[dst[e]], 1);
}

#define SCAN_T 256
#define SCAN_E 8
#define SCAN_CHUNK (SCAN_T * SCAN_E)

__global__ void k_scan1(const int* __restrict__ deg, int* __restrict__ outp,
                        int* __restrict__ bsum, int n) {
  __shared__ int sh[SCAN_T];
  int t = threadIdx.x;
  int base = blockIdx.x * SCAN_CHUNK + t * SCAN_E;
  int v[SCAN_E];
  int s = 0;
#pragma unroll
  for (int i = 0; i < SCAN_E; ++i) {
    int idx = base + i;
    int d = (idx < n) ? deg[idx] : 0;
    v[i] = s;
    s += d;
  }
  sh[t] = s;
  __syncthreads();
  for (int off = 1; off < SCAN_T; off <<= 1) {
    int add = (t >= off) ? sh[t - off] : 0;
    __syncthreads();
    sh[t] += add;
    __syncthreads();
  }
  int prefix = (t > 0) ? sh[t - 1] : 0;
#pragma unroll
  for (int i = 0; i < SCAN_E; ++i) {
    int idx = base + i;
    if (idx < n) outp[idx] = prefix + v[i];
  }
  if (t == SCAN_T - 1) bsum[blockIdx.x] = sh[t];
}

__global__ void k_scan2(int* bsum, int nb) {
  if (threadIdx.x == 0) {
    int s = 0;
    for (int i = 0; i < nb; ++i) {
      int d = bsum[i];
      bsum[i] = s;
      s += d;
    }
  }
}

__global__ void k_scan3(int* __restrict__ rp, const int* __restrict__ bsum,
                        int* __restrict__ cur, int n, int E) {
  int i = blockIdx.x * blockDim.x + threadIdx.x;
  if (i < n) {
    int v = rp[i] + bsum[i / SCAN_CHUNK];
    rp[i] = v;
    cur[i] = v;
  }
  if (i == 0) rp[n] = E;
}

__global__ void k_fill(const int* __restrict__ src, const int* __restrict__ dst,
                       int* __restrict__ cur, int* __restrict__ col, int E) {
  int e = blockIdx.x * blockDim.x + threadIdx.x;
  if (e < E) {
    int p = atomicAdd(&cur[dst[e]], 1);
    col[p] = src[e];
  }
}

// ---------------- conversions ----------------
__global__ void k_cvt(const float* __restrict__ in, ushort* __restrict__ out, int n4) {
  int i = blockIdx.x * blockDim.x + threadIdx.x;
  if (i >= n4) return;
  float4 v = ((const float4*)in)[i];
  uint2 o;
  o.x = (uint)f32_to_bf16(v.x) | ((uint)f32_to_bf16(v.y) << 16);
  o.y = (uint)f32_to_bf16(v.z) | ((uint)f32_to_bf16(v.w) << 16);
  ((uint2*)out)[i] = o;
}

struct P8 { const float* p[8]; };

__global__ void k_split(P8 w, ushort* __restrict__ hi, ushort* __restrict__ lo, int total) {
  int g = blockIdx.x * blockDim.x + threadIdx.x;
  if (g >= total) return;
  const int offs[8] = {0, 8192, 16384, 32768, 49152, 57344, 65536, 73728};
  int s = 0;
#pragma unroll
  for (int i = 1; i < 8; ++i) s += (g >= offs[i]);
  float w0 = w.p[s][g - offs[s]];
  ushort h = f32_to_bf16(w0);
  float r = w0 - bf16_to_f32(h);
  hi[g] = h;
  lo[g] = f32_to_bf16(r);
}

// ---------------- mean aggregation: wave per node, half-wave per edge slot ----------------
template <int F, bool OUTF32>
__global__ void k_agg(const ushort* __restrict__ x, const int* __restrict__ rp,
                      const int* __restrict__ col, void* __restrict__ outp, int n) {
  int w = (blockIdx.x * blockDim.x + threadIdx.x) >> 6;
  int lane = threadIdx.x & 63;
  if (w >= n) return;
  int h = lane >> 5;
  int l = lane & 31;
  int beg = rp[w], end = rp[w + 1];
  int deg = end - beg;
  constexpr int V = (F == 64) ? 2 : 4;
  float acc[V];
#pragma unroll
  for (int i = 0; i < V; ++i) acc[i] = 0.f;

  int j = beg + h;
  if (F == 64) {
    for (; j + 2 < end; j += 4) {
      int c0 = col[j], c1 = col[j + 2];
      uint v0 = *(const uint*)(x + (size_t)c0 * 64 + l * 2);
      uint v1 = *(const uint*)(x + (size_t)c1 * 64 + l * 2);
      acc[0] += __uint_as_float(v0 << 16) + __uint_as_float(v1 << 16);
      acc[1] += __uint_as_float(v0 & 0xffff0000u) + __uint_as_float(v1 & 0xffff0000u);
    }
    for (; j < end; j += 2) {
      int c0 = col[j];
      uint v0 = *(const uint*)(x + (size_t)c0 * 64 + l * 2);
      acc[0] += __uint_as_float(v0 << 16);
      acc[1] += __uint_as_float(v0 & 0xffff0000u);
    }
  } else {
    for (; j + 2 < end; j += 4) {
      int c0 = col[j], c1 = col[j + 2];
      uint2 v0 = *(const uint2*)(x + (size_t)c0 * 128 + l * 4);
      uint2 v1 = *(const uint2*)(x + (size_t)c1 * 128 + l * 4);
      acc[0] += __uint_as_float(v0.x << 16) + __uint_as_float(v1.x << 16);
      acc[1] += __uint_as_float(v0.x & 0xffff0000u) + __uint_as_float(v1.x & 0xffff0000u);
      acc[2] += __uint_as_float(v0.y << 16) + __uint_as_float(v1.y << 16);
      acc[3] += __uint_as_float(v0.y & 0xffff0000u) + __uint_as_float(v1.y & 0xffff0000u);
    }
    for (; j < end; j += 2) {
      int c0 = col[j];
      uint2 v0 = *(const uint2*)(x + (size_t)c0 * 128 + l * 4);
      acc[0] += __uint_as_float(v0.x << 16);
      acc[1] += __uint_as_float(v0.x & 0xffff0000u);
      acc[2] += __uint_as_float(v0.y << 16);
      acc[3] += __uint_as_float(v0.y & 0xffff0000u);
    }
  }
#pragma unroll
  for (int i = 0; i < V; ++i) acc[i] += __shfl_xor(acc[i], 32, 64);
  float inv = 1.0f / (float)(deg > 0 ? deg : 1);
  if (h == 0) {
    if (OUTF32) {
      float* o = (float*)outp + (size_t)w * F;
      if (F == 64) {
        ((float2*)o)[l] = make_float2(acc[0] * inv, acc[1] * inv);
      } else {
        ((float4*)o)[l] = make_float4(acc[0] * inv, acc[1] * inv, acc[2] * inv, acc[3] * inv);
      }
    } else {
      ushort* o = (ushort*)outp + (size_t)w * F;
      if (F == 64) {
        uint pk = (uint)f32_to_bf16(acc[0] * inv) | ((uint)f32_to_bf16(acc[1] * inv) << 16);
        ((uint*)o)[l] = pk;
      } else {
        uint2 pk;
        pk.x = (uint)f32_to_bf16(acc[0] * inv) | ((uint)f32_to_bf16(acc[1] * inv) << 16);
        pk.y = (uint)f32_to_bf16(acc[2] * inv) | ((uint)f32_to_bf16(acc[3] * inv) << 16);
        ((uint2*)o)[l] = pk;
      }
    }
  }
}

// ---------------- MFMA GEMM: out = act(A@Wa^T [+ B@Wb^T] + bias [+ addc]) ----------------
// W split hi/lo (2 MFMAs) for near-f32 weight accuracy. A,B,W are bf16 (ushort).
// OUTM: 0 = bf16 out, 1 = f32 out, 2 = both.
template <int K, int H, bool RELU, bool DUAL, bool ADDC, int OUTM>
__global__ __launch_bounds__(256, 1) void k_gemm(
    const ushort* __restrict__ A, const ushort* __restrict__ Wah, const ushort* __restrict__ Wal,
    const ushort* __restrict__ B, const ushort* __restrict__ Wbh, const ushort* __restrict__ Wbl,
    const float* __restrict__ bias, const float* __restrict__ addc,
    float* __restrict__ outf, ushort* __restrict__ outb, int n) {
  constexpr int BM = 128;
  constexpr int KT = 64;          // k-tile
  constexpr int NKT = K / KT;
  constexpr int MF = (H == 128) ? 4 : 2;  // 16-row frags per wave
  __shared__ ushort As[BM * KT];          // 16KB, XOR-swizzled
  __shared__ ushort Ws[2][H * KT];        // 16/32KB, hi+lo planes

  const int tid = threadIdx.x;
  const int lane = tid & 63;
  const int wid = tid >> 6;
  const int fr = lane & 15;
  const int fq = lane >> 4;
  const int blockRow = blockIdx.x * BM;
  const int rowBase = (H == 128) ? (wid >> 1) * 64 : wid * 32;
  const int colBase = (H == 128) ? (wid & 1) * 64 : 0;

  f32x4 acc[MF][4];
#pragma unroll
  for (int mi = 0; mi < MF; ++mi)
#pragma unroll
    for (int ni = 0; ni < 4; ++ni) acc[mi][ni] = (f32x4){0.f, 0.f, 0.f, 0.f};

#pragma unroll
  for (int phase = 0; phase < (DUAL ? 2 : 1); ++phase) {
    const ushort* __restrict__ Ap = phase ? B : A;
    const ushort* __restrict__ Wph = phase ? Wbh : Wah;
    const ushort* __restrict__ Wpl = phase ? Wbl : Wal;
#pragma unroll
    for (int kt = 0; kt < NKT; ++kt) {
      __syncthreads();
      // stage A (BM x KT), zero-padded rows beyond n
      for (int c = tid; c < BM * 8; c += 256) {
        int r = c >> 3, kc = c & 7;
        int row = blockRow + r;
        uint4 v = make_uint4(0u, 0u, 0u, 0u);
        if (row < n) v = *(const uint4*)(Ap + (size_t)row * K + kt * KT + kc * 8);
        *(uint4*)((char*)As + r * (KT * 2) + ((kc * 16) ^ ((r & 7) << 4))) = v;
      }
      // stage W hi/lo (H x KT)
      for (int c = tid; c < H * 8; c += 256) {
        int r = c >> 3, kc = c & 7;
        int boff = r * (KT * 2) + ((kc * 16) ^ ((r & 7) << 4));
        *(uint4*)((char*)Ws[0] + boff) = *(const uint4*)(Wph + (size_t)r * K + kt * KT + kc * 8);
        *(uint4*)((char*)Ws[1] + boff) = *(const uint4*)(Wpl + (size_t)r * K + kt * KT + kc * 8);
      }
      __syncthreads();
#pragma unroll
      for (int ks = 0; ks < 2; ++ks) {
        const int kb = ks * 64 + fq * 16;
        s16x8 af[MF], whf[4], wlf[4];
#pragma unroll
        for (int mi = 0; mi < MF; ++mi) {
          int r = rowBase + mi * 16 + fr;
          af[mi] = *(const s16x8*)((const char*)As + r * (KT * 2) + (kb ^ ((r & 7) << 4)));
        }
#pragma unroll
        for (int ni = 0; ni < 4; ++ni) {
          int r = colBase + ni * 16 + fr;
          int boff = r * (KT * 2) + (kb ^ ((r & 7) << 4));
          whf[ni] = *(const s16x8*)((const char*)Ws[0] + boff);
          wlf[ni] = *(const s16x8*)((const char*)Ws[1] + boff);
        }
#pragma unroll
        for (int mi = 0; mi < MF; ++mi)
#pragma unroll
          for (int ni = 0; ni < 4; ++ni) {
            acc[mi][ni] = __builtin_amdgcn_mfma_f32_16x16x32_bf16(af[mi], wlf[ni], acc[mi][ni], 0, 0, 0);
            acc[mi][ni] = __builtin_amdgcn_mfma_f32_16x16x32_bf16(af[mi], whf[ni], acc[mi][ni], 0, 0, 0);
          }
      }
    }
  }
  // epilogue: D frag mapping col=lane&15, row=(lane>>4)*4+reg
#pragma unroll
  for (int mi = 0; mi < MF; ++mi) {
#pragma unroll
    for (int ni = 0; ni < 4; ++ni) {
#pragma unroll
      for (int r = 0; r < 4; ++r) {
        int row = blockRow + rowBase + mi * 16 + fq * 4 + r;
        int colI = colBase + ni * 16 + fr;
        if (row < n) {
          float v = acc[mi][ni][r];
          if (bias) v += bias[colI];
          if (ADDC) v += addc[(size_t)row * H + colI];
          if (RELU) v = fmaxf(v, 0.f);
          if (OUTM >= 1) outf[(size_t)row * H + colI] = v;
          if (OUTM != 1) outb[(size_t)row * H + colI] = f32_to_bf16(v);
        }
      }
    }
  }
}

// ---------------- edge dot: half-wave per edge ----------------
__global__ void k_dot(const float* __restrict__ emb, const int* __restrict__ ea,
                      const int* __restrict__ eb, float* __restrict__ out, int ne) {
  int hw = (blockIdx.x * blockDim.x + threadIdx.x) >> 5;
  int l = threadIdx.x & 31;
  if (hw >= ne) return;
  float2 a = ((const float2*)(emb + (size_t)ea[hw] * 64))[l];
  float2 b = ((const float2*)(emb + (size_t)eb[hw] * 64))[l];
  float v = a.x * b.x + a.y * b.y;
#pragma unroll
  for (int off = 16; off; off >>= 1) v += __shfl_xor(v, off, 64);
  if (l == 0) out[hw] = v;
}

extern "C" void kernel_launch(void* const* d_in, const int* in_sizes, int n_in,
                              void* d_out, int out_size, void* d_ws, size_t ws_size,
                              hipStream_t stream) {
  const float* x = (const float*)d_in[0];
  const int* ei = (const int*)d_in[1];
  const int* es = (const int*)d_in[2];
  const float* b0 = (const float*)d_in[5];
  const float* b1 = (const float*)d_in[8];
  const float* b2 = (const float*)d_in[11];
  const float* bd1 = (const float*)d_in[13];
  const float* bd2 = (const float*)d_in[15];

  const int E = in_sizes[1] / 2;
  const int ES = in_sizes[2] / 2;
  const int* srcv = ei;
  const int* dstv = ei + E;
  const int* ea = es;
  const int* eb = es + ES;

  char* wp = (char*)d_ws;
  auto alloc = [&](size_t bytes) {
    char* p = wp;
    wp += (bytes + 511) & ~(size_t)511;
    return p;
  };
  int* row_ptr = (int*)alloc((NN + 1) * sizeof(int));
  int* cursor = (int*)alloc((size_t)NN * sizeof(int));
  int* colv = (int*)alloc((size_t)E * sizeof(int));
  int* bsum = (int*)alloc(256 * sizeof(int));
  ushort* xb = (ushort*)alloc((size_t)NN * 64 * 2);
  ushort* aggb = (ushort*)alloc((size_t)NN * 128 * 2);
  ushort* h1b = (ushort*)alloc((size_t)NN * 128 * 2);   // also rec1
  ushort* h2b = (ushort*)alloc((size_t)NN * 128 * 2);
  float* mf = (float*)alloc((size_t)NN * 64 * 4);
  ushort* embb = (ushort*)alloc((size_t)NN * 64 * 2);
  ushort* Whb = (ushort*)alloc(81920 * 2);
  ushort* Wlb = (ushort*)alloc(81920 * 2);

  // weight segment offsets: Wl0,Wr0,Wl1,Wr1,Wl2,Wr2,Wd1,Wd2
  const int WO0 = 0, WO1 = 8192, WO2 = 16384, WO3 = 32768, WO4 = 49152,
            WO5 = 57344, WO6 = 65536, WO7 = 73728;

  float* out_emb = (float*)d_out;
  float* out_rec = out_emb + (size_t)NN * 64;
  float* out_sc = out_rec + (size_t)NN * 64;

  // --- prep: CSR + conversions ---
  hipMemsetAsync(cursor, 0, (size_t)NN * sizeof(int), stream);
  k_count<<<(E + 255) / 256, 256, 0, stream>>>(dstv, cursor, E);
  int nb = (NN + SCAN_CHUNK - 1) / SCAN_CHUNK;
  k_scan1<<<nb, SCAN_T, 0, stream>>>(cursor, row_ptr, bsum, NN);
  k_scan2<<<1, 64, 0, stream>>>(bsum, nb);
  k_scan3<<<(NN + 255) / 256, 256, 0, stream>>>(row_ptr, bsum, cursor, NN, E);
  k_fill<<<(E + 255) / 256, 256, 0, stream>>>(srcv, dstv, cursor, colv, E);

  k_cvt<<<(NN * 64 / 4 + 255) / 256, 256, 0, stream>>>(x, xb, NN * 64 / 4);
  P8 wptrs;
  wptrs.p[0] = (const float*)d_in[3];  wptrs.p[1] = (const float*)d_in[4];
  wptrs.p[2] = (const float*)d_in[6];  wptrs.p[3] = (const float*)d_in[7];
  wptrs.p[4] = (const float*)d_in[9];  wptrs.p[5] = (const float*)d_in[10];
  wptrs.p[6] = (const float*)d_in[12]; wptrs.p[7] = (const float*)d_in[14];
  k_split<<<(81920 + 255) / 256, 256, 0, stream>>>(wptrs, Whb, Wlb, 81920);

  const int aggGrid = (NN + 3) / 4;
  dim3 g128((NN + 127) / 128);

  // layer 0
  k_agg<64, false><<<aggGrid, 256, 0, stream>>>(xb, row_ptr, colv, aggb, NN);
  k_gemm<64, 128, true, true, false, 0><<<g128, 256, 0, stream>>>(
      aggb, Whb + WO0, Wlb + WO0, xb, Whb + WO1, Wlb + WO1, b0, nullptr, nullptr, h1b, NN);
  // layer 1
  k_agg<128, false><<<aggGrid, 256, 0, stream>>>(h1b, row_ptr, colv, aggb, NN);
  k_gemm<128, 128, true, true, false, 0><<<g128, 256, 0, stream>>>(
      aggb, Whb + WO2, Wlb + WO2, h1b, Whb + WO3, Wlb + WO3, b1, nullptr, nullptr, h2b, NN);
  // layer 2: t = h2@Wl2^T (project first, then aggregate); emb = h2@Wr2^T + b2 + mean(t)
  k_gemm<128, 64, false, false, false, 0><<<g128, 256, 0, stream>>>(
      h2b, Whb + WO4, Wlb + WO4, nullptr, nullptr, nullptr, nullptr, nullptr, nullptr, aggb, NN);
  k_agg<64, true><<<aggGrid, 256, 0, stream>>>(aggb, row_ptr, colv, mf, NN);
  k_gemm<128, 64, false, false, true, 2><<<g128, 256, 0, stream>>>(
      h2b, Whb + WO5, Wlb + WO5, nullptr, nullptr, nullptr, b2, mf, out_emb, embb, NN);
  // decoder
  k_gemm<64, 128, true, false, false, 0><<<g128, 256, 0, stream>>>(
      embb, Whb + WO6, Wlb + WO6, nullptr, nullptr, nullptr, bd1, nullptr, nullptr, h1b, NN);
  k_gemm<128, 64, false, false, false, 1><<<g128, 256, 0, stream>>>(
      h1b, Whb + WO7, Wlb + WO7, nullptr, nullptr, nullptr, bd2, nullptr, out_rec, nullptr, NN);
  // edge scores
  k_dot<<<(ES + 7) / 8, 256, 0, stream>>>(out_emb, ea, eb, out_sc, ES);
}

// Round 3
// 485.433 us; speedup vs baseline: 2.2442x; 1.2064x over previous
//
#include <hip/hip_runtime.h>

#define NN 100000
#define RSZ 12500  // NN/8 nodes per XCD range
typedef unsigned int uint;
typedef unsigned short ushort;

using f32x4 = __attribute__((ext_vector_type(4))) float;
using s16x8 = __attribute__((ext_vector_type(8))) short;

__device__ inline ushort f32_to_bf16(float f) {
  uint u = __float_as_uint(f);
  uint r = (u + 0x7FFFu + ((u >> 16) & 1u)) >> 16;
  return (ushort)r;
}
__device__ inline float bf16_to_f32(ushort h) {
  return __uint_as_float(((uint)h) << 16);
}

struct P8 { const float* p[8]; };

// ---------------- fused prep: XCD-binned degree count + x->bf16 cvt + weight hi/lo split ----
__global__ void k_prep(const int* __restrict__ dst, int* __restrict__ deg, int E, int CB8,
                       const float* __restrict__ x, ushort* __restrict__ xb, int n4, int NC,
                       P8 w, ushort* __restrict__ whi, ushort* __restrict__ wlo, int wtotal) {
  int b = blockIdx.x;
  int tid = threadIdx.x;
  if (b < CB8) {
    // degree count, XCD-binned: range r = b&7 -> same-XCD L2 keeps deg slice resident
    int r = b & 7, cb = b >> 3;
    int lo = r * RSZ, hi = min(lo + RSZ, NN);
    int base = cb * 2048;
    int lim = min(base + 2048, E);
    for (int e = base + tid; e < lim; e += 256) {
      int d = dst[e];
      if (d >= lo && d < hi) atomicAdd(&deg[d], 1);
    }
  } else if (b < CB8 + NC) {
    int i = (b - CB8) * 256 + tid;
    if (i < n4) {
      float4 v = ((const float4*)x)[i];
      uint2 o;
      o.x = (uint)f32_to_bf16(v.x) | ((uint)f32_to_bf16(v.y) << 16);
      o.y = (uint)f32_to_bf16(v.z) | ((uint)f32_to_bf16(v.w) << 16);
      ((uint2*)xb)[i] = o;
    }
  } else {
    int g = (b - CB8 - NC) * 256 + tid;
    if (g < wtotal) {
      const int offs[8] = {0, 8192, 16384, 32768, 49152, 57344, 65536, 73728};
      int s = 0;
#pragma unroll
      for (int i = 1; i < 8; ++i) s += (g >= offs[i]);
      float w0 = w.p[s][g - offs[s]];
      ushort h = f32_to_bf16(w0);
      float rr = w0 - bf16_to_f32(h);
      whi[g] = h;
      wlo[g] = f32_to_bf16(rr);
    }
  }
}

#define SCAN_T 256
#define SCAN_E 8
#define SCAN_CHUNK (SCAN_T * SCAN_E)

__global__ void k_scan1(const int* __restrict__ deg, int* __restrict__ outp,
                        int* __restrict__ bsum, int n) {
  __shared__ int sh[SCAN_T];
  int t = threadIdx.x;
  int base = blockIdx.x * SCAN_CHUNK + t * SCAN_E;
  int v[SCAN_E];
  int s = 0;
#pragma unroll
  for (int i = 0; i < SCAN_E; ++i) {
    int idx = base + i;
    int d = (idx < n) ? deg[idx] : 0;
    v[i] = s;
    s += d;
  }
  sh[t] = s;
  __syncthreads();
  for (int off = 1; off < SCAN_T; off <<= 1) {
    int add = (t >= off) ? sh[t - off] : 0;
    __syncthreads();
    sh[t] += add;
    __syncthreads();
  }
  int prefix = (t > 0) ? sh[t - 1] : 0;
#pragma unroll
  for (int i = 0; i < SCAN_E; ++i) {
    int idx = base + i;
    if (idx < n) outp[idx] = prefix + v[i];
  }
  if (t == SCAN_T - 1) bsum[blockIdx.x] = sh[t];
}

__global__ void k_scan2(int* bsum, int nb) {
  if (threadIdx.x == 0) {
    int s = 0;
    for (int i = 0; i < nb; ++i) {
      int d = bsum[i];
      bsum[i] = s;
      s += d;
    }
  }
}

__global__ void k_scan3(int* __restrict__ rp, const int* __restrict__ bsum,
                        int* __restrict__ cur, int n, int E) {
  int i = blockIdx.x * blockDim.x + threadIdx.x;
  if (i < n) {
    int v = rp[i] + bsum[i / SCAN_CHUNK];
    rp[i] = v;
    cur[i] = v;
  }
  if (i == 0) rp[n] = E;
}

// ---------------- CSR fill, XCD-binned: col scatter + cursor atomics stay in one XCD's L2 ---
__global__ void k_fill2(const int* __restrict__ src, const int* __restrict__ dst,
                        int* __restrict__ cur, int* __restrict__ col, int E) {
  int r = blockIdx.x & 7, cb = blockIdx.x >> 3;
  int lo = r * RSZ, hi = min(lo + RSZ, NN);
  int base = cb * 2048;
  int lim = min(base + 2048, E);
  for (int e = base + threadIdx.x; e < lim; e += 256) {
    int d = dst[e];
    int s = src[e];  // unconditional coalesced load
    if (d >= lo && d < hi) {
      int p = atomicAdd(&cur[d], 1);
      col[p] = s;
    }
  }
}

// ---------------- mean aggregation: wave/node, G lanes per neighbor row (uint4/lane) -------
__device__ inline void acc8(float* acc, uint4 v) {
  acc[0] += __uint_as_float(v.x << 16);
  acc[1] += __uint_as_float(v.x & 0xffff0000u);
  acc[2] += __uint_as_float(v.y << 16);
  acc[3] += __uint_as_float(v.y & 0xffff0000u);
  acc[4] += __uint_as_float(v.z << 16);
  acc[5] += __uint_as_float(v.z & 0xffff0000u);
  acc[6] += __uint_as_float(v.w << 16);
  acc[7] += __uint_as_float(v.w & 0xffff0000u);
}

template <int F, bool OUTF32>
__global__ void k_agg(const ushort* __restrict__ x, const int* __restrict__ rp,
                      const int* __restrict__ col, void* __restrict__ outp, int n) {
  constexpr int G = F / 8;    // lanes per row (uint4 each): 8 or 16
  constexpr int NG = 64 / G;  // concurrent rows per wave: 8 or 4
  int w = (blockIdx.x * blockDim.x + threadIdx.x) >> 6;
  if (w >= n) return;
  int lane = threadIdx.x & 63;
  int g = lane / G, l = lane % G;
  int beg = rp[w], end = rp[w + 1];
  int deg = end - beg;
  float acc[8] = {0.f, 0.f, 0.f, 0.f, 0.f, 0.f, 0.f, 0.f};
  int j = beg + g;
  for (; j + NG < end; j += 2 * NG) {
    int c0 = col[j], c1 = col[j + NG];
    uint4 v0 = *((const uint4*)(x + (size_t)c0 * F) + l);
    uint4 v1 = *((const uint4*)(x + (size_t)c1 * F) + l);
    acc8(acc, v0);
    acc8(acc, v1);
  }
  if (j < end) {
    int c0 = col[j];
    uint4 v0 = *((const uint4*)(x + (size_t)c0 * F) + l);
    acc8(acc, v0);
  }
#pragma unroll
  for (int m = G; m < 64; m <<= 1)
#pragma unroll
    for (int i = 0; i < 8; ++i) acc[i] += __shfl_xor(acc[i], m, 64);
  if (g == 0) {
    float inv = 1.0f / (float)(deg > 0 ? deg : 1);
    if (OUTF32) {
      float* o = (float*)outp + (size_t)w * F + l * 8;
      ((float4*)o)[0] = make_float4(acc[0] * inv, acc[1] * inv, acc[2] * inv, acc[3] * inv);
      ((float4*)o)[1] = make_float4(acc[4] * inv, acc[5] * inv, acc[6] * inv, acc[7] * inv);
    } else {
      uint4 pk;
      pk.x = (uint)f32_to_bf16(acc[0] * inv) | ((uint)f32_to_bf16(acc[1] * inv) << 16);
      pk.y = (uint)f32_to_bf16(acc[2] * inv) | ((uint)f32_to_bf16(acc[3] * inv) << 16);
      pk.z = (uint)f32_to_bf16(acc[4] * inv) | ((uint)f32_to_bf16(acc[5] * inv) << 16);
      pk.w = (uint)f32_to_bf16(acc[6] * inv) | ((uint)f32_to_bf16(acc[7] * inv) << 16);
      *((uint4*)((ushort*)outp + (size_t)w * F) + l) = pk;
    }
  }
}

// ---------------- MFMA GEMM: out = act(A@Wa^T [+ B@Wb^T] + bias [+ addc]) ----------------
// W split hi/lo (2 MFMAs) for near-f32 weight accuracy. A,B,W are bf16 (ushort).
// OUTM: 0 = bf16 out, 1 = f32 out, 2 = both.
template <int K, int H, bool RELU, bool DUAL, bool ADDC, int OUTM>
__global__ __launch_bounds__(256, 1) void k_gemm(
    const ushort* __restrict__ A, const ushort* __restrict__ Wah, const ushort* __restrict__ Wal,
    const ushort* __restrict__ B, const ushort* __restrict__ Wbh, const ushort* __restrict__ Wbl,
    const float* __restrict__ bias, const float* __restrict__ addc,
    float* __restrict__ outf, ushort* __restrict__ outb, int n) {
  constexpr int BM = 128;
  constexpr int KT = 64;
  constexpr int NKT = K / KT;
  constexpr int MF = (H == 128) ? 4 : 2;
  __shared__ ushort As[BM * KT];
  __shared__ ushort Ws[2][H * KT];

  const int tid = threadIdx.x;
  const int lane = tid & 63;
  const int wid = tid >> 6;
  const int fr = lane & 15;
  const int fq = lane >> 4;
  const int blockRow = blockIdx.x * BM;
  const int rowBase = (H == 128) ? (wid >> 1) * 64 : wid * 32;
  const int colBase = (H == 128) ? (wid & 1) * 64 : 0;

  f32x4 acc[MF][4];
#pragma unroll
  for (int mi = 0; mi < MF; ++mi)
#pragma unroll
    for (int ni = 0; ni < 4; ++ni) acc[mi][ni] = (f32x4){0.f, 0.f, 0.f, 0.f};

#pragma unroll
  for (int phase = 0; phase < (DUAL ? 2 : 1); ++phase) {
    const ushort* __restrict__ Ap = phase ? B : A;
    const ushort* __restrict__ Wph = phase ? Wbh : Wah;
    const ushort* __restrict__ Wpl = phase ? Wbl : Wal;
#pragma unroll
    for (int kt = 0; kt < NKT; ++kt) {
      __syncthreads();
      for (int c = tid; c < BM * 8; c += 256) {
        int r = c >> 3, kc = c & 7;
        int row = blockRow + r;
        uint4 v = make_uint4(0u, 0u, 0u, 0u);
        if (row < n) v = *(const uint4*)(Ap + (size_t)row * K + kt * KT + kc * 8);
        *(uint4*)((char*)As + r * (KT * 2) + ((kc * 16) ^ ((r & 7) << 4))) = v;
      }
      for (int c = tid; c < H * 8; c += 256) {
        int r = c >> 3, kc = c & 7;
        int boff = r * (KT * 2) + ((kc * 16) ^ ((r & 7) << 4));
        *(uint4*)((char*)Ws[0] + boff) = *(const uint4*)(Wph + (size_t)r * K + kt * KT + kc * 8);
        *(uint4*)((char*)Ws[1] + boff) = *(const uint4*)(Wpl + (size_t)r * K + kt * KT + kc * 8);
      }
      __syncthreads();
#pragma unroll
      for (int ks = 0; ks < 2; ++ks) {
        const int kb = ks * 64 + fq * 16;
        s16x8 af[MF], whf[4], wlf[4];
#pragma unroll
        for (int mi = 0; mi < MF; ++mi) {
          int r = rowBase + mi * 16 + fr;
          af[mi] = *(const s16x8*)((const char*)As + r * (KT * 2) + (kb ^ ((r & 7) << 4)));
        }
#pragma unroll
        for (int ni = 0; ni < 4; ++ni) {
          int r = colBase + ni * 16 + fr;
          int boff = r * (KT * 2) + (kb ^ ((r & 7) << 4));
          whf[ni] = *(const s16x8*)((const char*)Ws[0] + boff);
          wlf[ni] = *(const s16x8*)((const char*)Ws[1] + boff);
        }
#pragma unroll
        for (int mi = 0; mi < MF; ++mi)
#pragma unroll
          for (int ni = 0; ni < 4; ++ni) {
            acc[mi][ni] = __builtin_amdgcn_mfma_f32_16x16x32_bf16(af[mi], wlf[ni], acc[mi][ni], 0, 0, 0);
            acc[mi][ni] = __builtin_amdgcn_mfma_f32_16x16x32_bf16(af[mi], whf[ni], acc[mi][ni], 0, 0, 0);
          }
      }
    }
  }
#pragma unroll
  for (int mi = 0; mi < MF; ++mi) {
#pragma unroll
    for (int ni = 0; ni < 4; ++ni) {
#pragma unroll
      for (int r = 0; r < 4; ++r) {
        int row = blockRow + rowBase + mi * 16 + fq * 4 + r;
        int colI = colBase + ni * 16 + fr;
        if (row < n) {
          float v = acc[mi][ni][r];
          if (bias) v += bias[colI];
          if (ADDC) v += addc[(size_t)row * H + colI];
          if (RELU) v = fmaxf(v, 0.f);
          if (OUTM >= 1) outf[(size_t)row * H + colI] = v;
          if (OUTM != 1) outb[(size_t)row * H + colI] = f32_to_bf16(v);
        }
      }
    }
  }
}

// ---------------- edge dot: half-wave per edge ----------------
__global__ void k_dot(const float* __restrict__ emb, const int* __restrict__ ea,
                      const int* __restrict__ eb, float* __restrict__ out, int ne) {
  int hw = (blockIdx.x * blockDim.x + threadIdx.x) >> 5;
  int l = threadIdx.x & 31;
  if (hw >= ne) return;
  float2 a = ((const float2*)(emb + (size_t)ea[hw] * 64))[l];
  float2 b = ((const float2*)(emb + (size_t)eb[hw] * 64))[l];
  float v = a.x * b.x + a.y * b.y;
#pragma unroll
  for (int off = 16; off; off >>= 1) v += __shfl_xor(v, off, 64);
  if (l == 0) out[hw] = v;
}

extern "C" void kernel_launch(void* const* d_in, const int* in_sizes, int n_in,
                              void* d_out, int out_size, void* d_ws, size_t ws_size,
                              hipStream_t stream) {
  const float* x = (const float*)d_in[0];
  const int* ei = (const int*)d_in[1];
  const int* es = (const int*)d_in[2];
  const float* b0 = (const float*)d_in[5];
  const float* b1 = (const float*)d_in[8];
  const float* b2 = (const float*)d_in[11];
  const float* bd1 = (const float*)d_in[13];
  const float* bd2 = (const float*)d_in[15];

  const int E = in_sizes[1] / 2;
  const int ES = in_sizes[2] / 2;
  const int* srcv = ei;
  const int* dstv = ei + E;
  const int* ea = es;
  const int* eb = es + ES;

  char* wp = (char*)d_ws;
  auto alloc = [&](size_t bytes) {
    char* p = wp;
    wp += (bytes + 511) & ~(size_t)511;
    return p;
  };
  int* row_ptr = (int*)alloc((NN + 1) * sizeof(int));
  int* cursor = (int*)alloc((size_t)NN * sizeof(int));
  int* colv = (int*)alloc((size_t)E * sizeof(int));
  int* bsum = (int*)alloc(256 * sizeof(int));
  ushort* xb = (ushort*)alloc((size_t)NN * 64 * 2);
  ushort* aggb = (ushort*)alloc((size_t)NN * 128 * 2);
  ushort* h1b = (ushort*)alloc((size_t)NN * 128 * 2);
  ushort* h2b = (ushort*)alloc((size_t)NN * 128 * 2);
  float* mf = (float*)alloc((size_t)NN * 64 * 4);
  ushort* embb = (ushort*)alloc((size_t)NN * 64 * 2);
  ushort* Whb = (ushort*)alloc(81920 * 2);
  ushort* Wlb = (ushort*)alloc(81920 * 2);

  const int WO0 = 0, WO1 = 8192, WO2 = 16384, WO3 = 32768, WO4 = 49152,
            WO5 = 57344, WO6 = 65536, WO7 = 73728;

  float* out_emb = (float*)d_out;
  float* out_rec = out_emb + (size_t)NN * 64;
  float* out_sc = out_rec + (size_t)NN * 64;

  hipMemsetAsync(cursor, 0, (size_t)NN * sizeof(int), stream);

  P8 wptrs;
  wptrs.p[0] = (const float*)d_in[3];  wptrs.p[1] = (const float*)d_in[4];
  wptrs.p[2] = (const float*)d_in[6];  wptrs.p[3] = (const float*)d_in[7];
  wptrs.p[4] = (const float*)d_in[9];  wptrs.p[5] = (const float*)d_in[10];
  wptrs.p[6] = (const float*)d_in[12]; wptrs.p[7] = (const float*)d_in[14];

  const int CB = (E + 2047) / 2048;
  const int CB8 = CB * 8;
  const int n4 = NN * 64 / 4;
  const int NC = (n4 + 255) / 256;
  const int NS = (81920 + 255) / 256;
  k_prep<<<CB8 + NC + NS, 256, 0, stream>>>(dstv, cursor, E, CB8, x, xb, n4, NC,
                                            wptrs, Whb, Wlb, 81920);
  int nb = (NN + SCAN_CHUNK - 1) / SCAN_CHUNK;
  k_scan1<<<nb, SCAN_T, 0, stream>>>(cursor, row_ptr, bsum, NN);
  k_scan2<<<1, 64, 0, stream>>>(bsum, nb);
  k_scan3<<<(NN + 255) / 256, 256, 0, stream>>>(row_ptr, bsum, cursor, NN, E);
  k_fill2<<<CB8, 256, 0, stream>>>(srcv, dstv, cursor, colv, E);

  const int aggGrid = (NN + 3) / 4;
  dim3 g128((NN + 127) / 128);

  // layer 0
  k_agg<64, false><<<aggGrid, 256, 0, stream>>>(xb, row_ptr, colv, aggb, NN);
  k_gemm<64, 128, true, true, false, 0><<<g128, 256, 0, stream>>>(
      aggb, Whb + WO0, Wlb + WO0, xb, Whb + WO1, Wlb + WO1, b0, nullptr, nullptr, h1b, NN);
  // layer 1
  k_agg<128, false><<<aggGrid, 256, 0, stream>>>(h1b, row_ptr, colv, aggb, NN);
  k_gemm<128, 128, true, true, false, 0><<<g128, 256, 0, stream>>>(
      aggb, Whb + WO2, Wlb + WO2, h1b, Whb + WO3, Wlb + WO3, b1, nullptr, nullptr, h2b, NN);
  // layer 2: project h2@Wl2^T first, aggregate the 64-wide result, add h2@Wr2^T + b2
  k_gemm<128, 64, false, false, false, 0><<<g128, 256, 0, stream>>>(
      h2b, Whb + WO4, Wlb + WO4, nullptr, nullptr, nullptr, nullptr, nullptr, nullptr, aggb, NN);
  k_agg<64, true><<<aggGrid, 256, 0, stream>>>(aggb, row_ptr, colv, mf, NN);
  k_gemm<128, 64, false, false, true, 2><<<g128, 256, 0, stream>>>(
      h2b, Whb + WO5, Wlb + WO5, nullptr, nullptr, nullptr, b2, mf, out_emb, embb, NN);
  // decoder
  k_gemm<64, 128, true, false, false, 0><<<g128, 256, 0, stream>>>(
      embb, Whb + WO6, Wlb + WO6, nullptr, nullptr, nullptr, bd1, nullptr, nullptr, h1b, NN);
  k_gemm<128, 64, false, false, false, 1><<<g128, 256, 0, stream>>>(
      h1b, Whb + WO7, Wlb + WO7, nullptr, nullptr, nullptr, bd2, nullptr, out_rec, nullptr, NN);
  // edge scores
  k_dot<<<(ES + 7) / 8, 256, 0, stream>>>(out_emb, ea, eb, out_sc, ES);
}

// Round 4
// 406.390 us; speedup vs baseline: 2.6807x; 1.1945x over previous
//
#include <hip/hip_runtime.h>

#define NN 100000
#define NBK 98      // node buckets: bucket = dst >> 10 (1024 nodes each)
#define CHUNK 8192  // edges per block in bucket passes
typedef unsigned int uint;
typedef unsigned short ushort;

using f32x4 = __attribute__((ext_vector_type(4))) float;
using s16x8 = __attribute__((ext_vector_type(8))) short;

__device__ inline ushort f32_to_bf16(float f) {
  uint u = __float_as_uint(f);
  uint r = (u + 0x7FFFu + ((u >> 16) & 1u)) >> 16;
  return (ushort)r;
}
__device__ inline float bf16_to_f32(ushort h) {
  return __uint_as_float(((uint)h) << 16);
}

struct P8 { const float* p[8]; };

// ---- fused prep: bucket-count (LDS hist, no per-edge global atomics) + cvt + weight split
__global__ void k_prep(const int* __restrict__ dst, uint* __restrict__ bcnt, int E, int NCB,
                       const float* __restrict__ x, ushort* __restrict__ xb, int n4, int NC,
                       P8 w, ushort* __restrict__ whi, ushort* __restrict__ wlo, int wtotal) {
  int b = blockIdx.x;
  int tid = threadIdx.x;
  if (b < NCB) {
    __shared__ uint hist[NBK];
    for (int i = tid; i < NBK; i += 256) hist[i] = 0;
    __syncthreads();
    int base = b * CHUNK;
    int lim = min(base + CHUNK, E);
    for (int e = base + tid; e < lim; e += 256) atomicAdd(&hist[(uint)dst[e] >> 10], 1u);
    __syncthreads();
    for (int i = tid; i < NBK; i += 256)
      if (hist[i]) atomicAdd(&bcnt[i], hist[i]);
  } else if (b < NCB + NC) {
    int i = (b - NCB) * 256 + tid;
    if (i < n4) {
      float4 v = ((const float4*)x)[i];
      uint2 o;
      o.x = (uint)f32_to_bf16(v.x) | ((uint)f32_to_bf16(v.y) << 16);
      o.y = (uint)f32_to_bf16(v.z) | ((uint)f32_to_bf16(v.w) << 16);
      ((uint2*)xb)[i] = o;
    }
  } else {
    int g = (b - NCB - NC) * 256 + tid;
    if (g < wtotal) {
      const int offs[8] = {0, 8192, 16384, 32768, 49152, 57344, 65536, 73728};
      int s = 0;
#pragma unroll
      for (int i = 1; i < 8; ++i) s += (g >= offs[i]);
      float w0 = w.p[s][g - offs[s]];
      ushort h = f32_to_bf16(w0);
      float rr = w0 - bf16_to_f32(h);
      whi[g] = h;
      wlo[g] = f32_to_bf16(rr);
    }
  }
}

// ---- tiny scan of 98 bucket counts -> bases + cursors; also rp[NN]=E
__global__ void k_bscan(const uint* __restrict__ bcnt, uint* __restrict__ bbase,
                        uint* __restrict__ bcur, int* __restrict__ rp) {
  if (threadIdx.x == 0) {
    uint s = 0;
    for (int i = 0; i < NBK; ++i) {
      uint c = bcnt[i];
      bbase[i] = s;
      bcur[i] = s;
      s += c;
    }
    bbase[NBK] = s;
    rp[NN] = (int)s;
  }
}

// ---- scatter edges into bucket regions as packed (dstLocal<<20 | src)
__global__ void k_bscatter(const int* __restrict__ src, const int* __restrict__ dst,
                           uint* __restrict__ bcur, uint* __restrict__ packed, int E) {
  __shared__ uint hist[NBK], runbase[NBK], cur[NBK];
  int tid = threadIdx.x;
  for (int i = tid; i < NBK; i += 256) hist[i] = 0;
  __syncthreads();
  int base = blockIdx.x * CHUNK;
  int lim = min(base + CHUNK, E);
  for (int e = base + tid; e < lim; e += 256) atomicAdd(&hist[(uint)dst[e] >> 10], 1u);
  __syncthreads();
  for (int i = tid; i < NBK; i += 256) {
    runbase[i] = hist[i] ? atomicAdd(&bcur[i], hist[i]) : 0u;
    cur[i] = 0;
  }
  __syncthreads();
  for (int e = base + tid; e < lim; e += 256) {
    uint d = (uint)dst[e];
    uint s = (uint)src[e];
    uint bk = d >> 10;
    uint p = runbase[bk] + atomicAdd(&cur[bk], 1u);
    packed[p] = ((d & 1023u) << 20) | s;
  }
}

// ---- per-bucket CSR build: LDS hist + scan -> row_ptr + col (contiguous region per bucket)
__global__ void k_build(const uint* __restrict__ bbase, const uint* __restrict__ packed,
                        int* __restrict__ rp, int* __restrict__ col) {
  __shared__ uint hist[1024];
  __shared__ uint ws[256];
  int b = blockIdx.x;
  int tid = threadIdx.x;
  uint lo = bbase[b], hi = bbase[b + 1];
#pragma unroll
  for (int i = 0; i < 4; ++i) hist[tid + i * 256] = 0;
  __syncthreads();
  for (uint e = lo + tid; e < hi; e += 256) atomicAdd(&hist[packed[e] >> 20], 1u);
  __syncthreads();
  // exclusive scan of hist[1024]: 4 per thread + block scan
  uint v0 = hist[tid * 4], v1 = hist[tid * 4 + 1], v2 = hist[tid * 4 + 2], v3 = hist[tid * 4 + 3];
  ws[tid] = v0 + v1 + v2 + v3;
  __syncthreads();
  for (int off = 1; off < 256; off <<= 1) {
    uint add = (tid >= off) ? ws[tid - off] : 0u;
    __syncthreads();
    ws[tid] += add;
    __syncthreads();
  }
  uint ex = (tid > 0) ? ws[tid - 1] : 0u;
  hist[tid * 4] = ex;
  hist[tid * 4 + 1] = ex + v0;
  hist[tid * 4 + 2] = ex + v0 + v1;
  hist[tid * 4 + 3] = ex + v0 + v1 + v2;
  // row_ptr for this bucket's nodes
  int nodeBase = b << 10;
#pragma unroll
  for (int i = 0; i < 4; ++i) {
    int node = nodeBase + tid * 4 + i;
    if (node < NN) rp[node] = (int)(lo + hist[tid * 4 + i]);
  }
  __syncthreads();
  // place edges (hist becomes cursor)
  for (uint e = lo + tid; e < hi; e += 256) {
    uint pk = packed[e];
    uint p = atomicAdd(&hist[pk >> 20], 1u);
    col[lo + p] = (int)(pk & 0xFFFFFu);
  }
}

// ---------------- mean aggregation: wave/node, G lanes per neighbor row (uint4/lane) -------
__device__ inline void acc8(float* acc, uint4 v) {
  acc[0] += __uint_as_float(v.x << 16);
  acc[1] += __uint_as_float(v.x & 0xffff0000u);
  acc[2] += __uint_as_float(v.y << 16);
  acc[3] += __uint_as_float(v.y & 0xffff0000u);
  acc[4] += __uint_as_float(v.z << 16);
  acc[5] += __uint_as_float(v.z & 0xffff0000u);
  acc[6] += __uint_as_float(v.w << 16);
  acc[7] += __uint_as_float(v.w & 0xffff0000u);
}

template <int F, bool OUTF32>
__global__ void k_agg(const ushort* __restrict__ x, const int* __restrict__ rp,
                      const int* __restrict__ col, void* __restrict__ outp, int n) {
  constexpr int G = F / 8;
  constexpr int NG = 64 / G;
  int w = (blockIdx.x * blockDim.x + threadIdx.x) >> 6;
  if (w >= n) return;
  int lane = threadIdx.x & 63;
  int g = lane / G, l = lane % G;
  int beg = rp[w], end = rp[w + 1];
  int deg = end - beg;
  float acc[8] = {0.f, 0.f, 0.f, 0.f, 0.f, 0.f, 0.f, 0.f};
  int j = beg + g;
  for (; j + NG < end; j += 2 * NG) {
    int c0 = col[j], c1 = col[j + NG];
    uint4 v0 = *((const uint4*)(x + (size_t)c0 * F) + l);
    uint4 v1 = *((const uint4*)(x + (size_t)c1 * F) + l);
    acc8(acc, v0);
    acc8(acc, v1);
  }
  if (j < end) {
    int c0 = col[j];
    uint4 v0 = *((const uint4*)(x + (size_t)c0 * F) + l);
    acc8(acc, v0);
  }
#pragma unroll
  for (int m = G; m < 64; m <<= 1)
#pragma unroll
    for (int i = 0; i < 8; ++i) acc[i] += __shfl_xor(acc[i], m, 64);
  if (g == 0) {
    float inv = 1.0f / (float)(deg > 0 ? deg : 1);
    if (OUTF32) {
      float* o = (float*)outp + (size_t)w * F + l * 8;
      ((float4*)o)[0] = make_float4(acc[0] * inv, acc[1] * inv, acc[2] * inv, acc[3] * inv);
      ((float4*)o)[1] = make_float4(acc[4] * inv, acc[5] * inv, acc[6] * inv, acc[7] * inv);
    } else {
      uint4 pk;
      pk.x = (uint)f32_to_bf16(acc[0] * inv) | ((uint)f32_to_bf16(acc[1] * inv) << 16);
      pk.y = (uint)f32_to_bf16(acc[2] * inv) | ((uint)f32_to_bf16(acc[3] * inv) << 16);
      pk.z = (uint)f32_to_bf16(acc[4] * inv) | ((uint)f32_to_bf16(acc[5] * inv) << 16);
      pk.w = (uint)f32_to_bf16(acc[6] * inv) | ((uint)f32_to_bf16(acc[7] * inv) << 16);
      *((uint4*)((ushort*)outp + (size_t)w * F) + l) = pk;
    }
  }
}

// ---------------- MFMA GEMM: out = act(A@Wa^T [+ B@Wb^T] + bias [+ addc]) ----------------
template <int K, int H, bool RELU, bool DUAL, bool ADDC, int OUTM>
__global__ __launch_bounds__(256, 1) void k_gemm(
    const ushort* __restrict__ A, const ushort* __restrict__ Wah, const ushort* __restrict__ Wal,
    const ushort* __restrict__ B, const ushort* __restrict__ Wbh, const ushort* __restrict__ Wbl,
    const float* __restrict__ bias, const float* __restrict__ addc,
    float* __restrict__ outf, ushort* __restrict__ outb, int n) {
  constexpr int BM = 128;
  constexpr int KT = 64;
  constexpr int NKT = K / KT;
  constexpr int MF = (H == 128) ? 4 : 2;
  __shared__ ushort As[BM * KT];
  __shared__ ushort Ws[2][H * KT];

  const int tid = threadIdx.x;
  const int lane = tid & 63;
  const int wid = tid >> 6;
  const int fr = lane & 15;
  const int fq = lane >> 4;
  const int blockRow = blockIdx.x * BM;
  const int rowBase = (H == 128) ? (wid >> 1) * 64 : wid * 32;
  const int colBase = (H == 128) ? (wid & 1) * 64 : 0;

  f32x4 acc[MF][4];
#pragma unroll
  for (int mi = 0; mi < MF; ++mi)
#pragma unroll
    for (int ni = 0; ni < 4; ++ni) acc[mi][ni] = (f32x4){0.f, 0.f, 0.f, 0.f};

#pragma unroll
  for (int phase = 0; phase < (DUAL ? 2 : 1); ++phase) {
    const ushort* __restrict__ Ap = phase ? B : A;
    const ushort* __restrict__ Wph = phase ? Wbh : Wah;
    const ushort* __restrict__ Wpl = phase ? Wbl : Wal;
#pragma unroll
    for (int kt = 0; kt < NKT; ++kt) {
      __syncthreads();
      for (int c = tid; c < BM * 8; c += 256) {
        int r = c >> 3, kc = c & 7;
        int row = blockRow + r;
        uint4 v = make_uint4(0u, 0u, 0u, 0u);
        if (row < n) v = *(const uint4*)(Ap + (size_t)row * K + kt * KT + kc * 8);
        *(uint4*)((char*)As + r * (KT * 2) + ((kc * 16) ^ ((r & 7) << 4))) = v;
      }
      for (int c = tid; c < H * 8; c += 256) {
        int r = c >> 3, kc = c & 7;
        int boff = r * (KT * 2) + ((kc * 16) ^ ((r & 7) << 4));
        *(uint4*)((char*)Ws[0] + boff) = *(const uint4*)(Wph + (size_t)r * K + kt * KT + kc * 8);
        *(uint4*)((char*)Ws[1] + boff) = *(const uint4*)(Wpl + (size_t)r * K + kt * KT + kc * 8);
      }
      __syncthreads();
#pragma unroll
      for (int ks = 0; ks < 2; ++ks) {
        const int kb = ks * 64 + fq * 16;
        s16x8 af[MF], whf[4], wlf[4];
#pragma unroll
        for (int mi = 0; mi < MF; ++mi) {
          int r = rowBase + mi * 16 + fr;
          af[mi] = *(const s16x8*)((const char*)As + r * (KT * 2) + (kb ^ ((r & 7) << 4)));
        }
#pragma unroll
        for (int ni = 0; ni < 4; ++ni) {
          int r = colBase + ni * 16 + fr;
          int boff = r * (KT * 2) + (kb ^ ((r & 7) << 4));
          whf[ni] = *(const s16x8*)((const char*)Ws[0] + boff);
          wlf[ni] = *(const s16x8*)((const char*)Ws[1] + boff);
        }
#pragma unroll
        for (int mi = 0; mi < MF; ++mi)
#pragma unroll
          for (int ni = 0; ni < 4; ++ni) {
            acc[mi][ni] = __builtin_amdgcn_mfma_f32_16x16x32_bf16(af[mi], wlf[ni], acc[mi][ni], 0, 0, 0);
            acc[mi][ni] = __builtin_amdgcn_mfma_f32_16x16x32_bf16(af[mi], whf[ni], acc[mi][ni], 0, 0, 0);
          }
      }
    }
  }
#pragma unroll
  for (int mi = 0; mi < MF; ++mi) {
#pragma unroll
    for (int ni = 0; ni < 4; ++ni) {
#pragma unroll
      for (int r = 0; r < 4; ++r) {
        int row = blockRow + rowBase + mi * 16 + fq * 4 + r;
        int colI = colBase + ni * 16 + fr;
        if (row < n) {
          float v = acc[mi][ni][r];
          if (bias) v += bias[colI];
          if (ADDC) v += addc[(size_t)row * H + colI];
          if (RELU) v = fmaxf(v, 0.f);
          if (OUTM >= 1) outf[(size_t)row * H + colI] = v;
          if (OUTM != 1) outb[(size_t)row * H + colI] = f32_to_bf16(v);
        }
      }
    }
  }
}

// ---------------- edge dot: half-wave per edge ----------------
__global__ void k_dot(const float* __restrict__ emb, const int* __restrict__ ea,
                      const int* __restrict__ eb, float* __restrict__ out, int ne) {
  int hw = (blockIdx.x * blockDim.x + threadIdx.x) >> 5;
  int l = threadIdx.x & 31;
  if (hw >= ne) return;
  float2 a = ((const float2*)(emb + (size_t)ea[hw] * 64))[l];
  float2 b = ((const float2*)(emb + (size_t)eb[hw] * 64))[l];
  float v = a.x * b.x + a.y * b.y;
#pragma unroll
  for (int off = 16; off; off >>= 1) v += __shfl_xor(v, off, 64);
  if (l == 0) out[hw] = v;
}

extern "C" void kernel_launch(void* const* d_in, const int* in_sizes, int n_in,
                              void* d_out, int out_size, void* d_ws, size_t ws_size,
                              hipStream_t stream) {
  const float* x = (const float*)d_in[0];
  const int* ei = (const int*)d_in[1];
  const int* es = (const int*)d_in[2];
  const float* b0 = (const float*)d_in[5];
  const float* b1 = (const float*)d_in[8];
  const float* b2 = (const float*)d_in[11];
  const float* bd1 = (const float*)d_in[13];
  const float* bd2 = (const float*)d_in[15];

  const int E = in_sizes[1] / 2;
  const int ES = in_sizes[2] / 2;
  const int* srcv = ei;
  const int* dstv = ei + E;
  const int* ea = es;
  const int* eb = es + ES;

  char* wp = (char*)d_ws;
  auto alloc = [&](size_t bytes) {
    char* p = wp;
    wp += (bytes + 511) & ~(size_t)511;
    return p;
  };
  int* row_ptr = (int*)alloc((NN + 1) * sizeof(int));
  uint* bcnt = (uint*)alloc(NBK * sizeof(uint));
  uint* bbase = (uint*)alloc((NBK + 1) * sizeof(uint));
  uint* bcur = (uint*)alloc(NBK * sizeof(uint));
  uint* packed = (uint*)alloc((size_t)E * sizeof(uint));
  int* colv = (int*)alloc((size_t)E * sizeof(int));
  ushort* xb = (ushort*)alloc((size_t)NN * 64 * 2);
  ushort* aggb = (ushort*)alloc((size_t)NN * 128 * 2);
  ushort* h1b = (ushort*)alloc((size_t)NN * 128 * 2);
  ushort* h2b = (ushort*)alloc((size_t)NN * 128 * 2);
  float* mf = (float*)alloc((size_t)NN * 64 * 4);
  ushort* embb = (ushort*)alloc((size_t)NN * 64 * 2);
  ushort* Whb = (ushort*)alloc(81920 * 2);
  ushort* Wlb = (ushort*)alloc(81920 * 2);

  const int WO0 = 0, WO1 = 8192, WO2 = 16384, WO3 = 32768, WO4 = 49152,
            WO5 = 57344, WO6 = 65536, WO7 = 73728;

  float* out_emb = (float*)d_out;
  float* out_rec = out_emb + (size_t)NN * 64;
  float* out_sc = out_rec + (size_t)NN * 64;

  hipMemsetAsync(bcnt, 0, NBK * sizeof(uint), stream);

  P8 wptrs;
  wptrs.p[0] = (const float*)d_in[3];  wptrs.p[1] = (const float*)d_in[4];
  wptrs.p[2] = (const float*)d_in[6];  wptrs.p[3] = (const float*)d_in[7];
  wptrs.p[4] = (const float*)d_in[9];  wptrs.p[5] = (const float*)d_in[10];
  wptrs.p[6] = (const float*)d_in[12]; wptrs.p[7] = (const float*)d_in[14];

  const int NCB = (E + CHUNK - 1) / CHUNK;
  const int n4 = NN * 64 / 4;
  const int NC = (n4 + 255) / 256;
  const int NS = (81920 + 255) / 256;
  k_prep<<<NCB + NC + NS, 256, 0, stream>>>(dstv, bcnt, E, NCB, x, xb, n4, NC,
                                            wptrs, Whb, Wlb, 81920);
  k_bscan<<<1, 64, 0, stream>>>(bcnt, bbase, bcur, row_ptr);
  k_bscatter<<<NCB, 256, 0, stream>>>(srcv, dstv, bcur, packed, E);
  k_build<<<NBK, 256, 0, stream>>>(bbase, packed, row_ptr, colv);

  const int aggGrid = (NN + 3) / 4;
  dim3 g128((NN + 127) / 128);

  // layer 0
  k_agg<64, false><<<aggGrid, 256, 0, stream>>>(xb, row_ptr, colv, aggb, NN);
  k_gemm<64, 128, true, true, false, 0><<<g128, 256, 0, stream>>>(
      aggb, Whb + WO0, Wlb + WO0, xb, Whb + WO1, Wlb + WO1, b0, nullptr, nullptr, h1b, NN);
  // layer 1
  k_agg<128, false><<<aggGrid, 256, 0, stream>>>(h1b, row_ptr, colv, aggb, NN);
  k_gemm<128, 128, true, true, false, 0><<<g128, 256, 0, stream>>>(
      aggb, Whb + WO2, Wlb + WO2, h1b, Whb + WO3, Wlb + WO3, b1, nullptr, nullptr, h2b, NN);
  // layer 2: project h2@Wl2^T first, aggregate the 64-wide result, add h2@Wr2^T + b2
  k_gemm<128, 64, false, false, false, 0><<<g128, 256, 0, stream>>>(
      h2b, Whb + WO4, Wlb + WO4, nullptr, nullptr, nullptr, nullptr, nullptr, nullptr, aggb, NN);
  k_agg<64, true><<<aggGrid, 256, 0, stream>>>(aggb, row_ptr, colv, mf, NN);
  k_gemm<128, 64, false, false, true, 2><<<g128, 256, 0, stream>>>(
      h2b, Whb + WO5, Wlb + WO5, nullptr, nullptr, nullptr, b2, mf, out_emb, embb, NN);
  // decoder
  k_gemm<64, 128, true, false, false, 0><<<g128, 256, 0, stream>>>(
      embb, Whb + WO6, Wlb + WO6, nullptr, nullptr, nullptr, bd1, nullptr, nullptr, h1b, NN);
  k_gemm<128, 64, false, false, false, 1><<<g128, 256, 0, stream>>>(
      h1b, Whb + WO7, Wlb + WO7, nullptr, nullptr, nullptr, bd2, nullptr, out_rec, nullptr, NN);
  // edge scores
  k_dot<<<(ES + 7) / 8, 256, 0, stream>>>(out_emb, ea, eb, out_sc, ES);
}

// Round 5
// 404.498 us; speedup vs baseline: 2.6932x; 1.0047x over previous
//
#include <hip/hip_runtime.h>

#define NN 100000
#define NBK 98      // node buckets: bucket = dst >> 10 (1024 nodes each)
#define CHUNK 8192  // edges per block in bucket passes
typedef unsigned int uint;
typedef unsigned short ushort;

using f32x4 = __attribute__((ext_vector_type(4))) float;
using s16x8 = __attribute__((ext_vector_type(8))) short;

__device__ inline ushort f32_to_bf16(float f) {
  uint u = __float_as_uint(f);
  uint r = (u + 0x7FFFu + ((u >> 16) & 1u)) >> 16;
  return (ushort)r;
}
__device__ inline float bf16_to_f32(ushort h) {
  return __uint_as_float(((uint)h) << 16);
}

struct P8 { const float* p[8]; };

// ---- fused prep: bucket-count (LDS hist) + x->bf16 cvt + weight hi/lo split
__global__ void k_prep(const int* __restrict__ dst, uint* __restrict__ bcnt, int E, int NCB,
                       const float* __restrict__ x, ushort* __restrict__ xb, int n4, int NC,
                       P8 w, ushort* __restrict__ whi, ushort* __restrict__ wlo, int wtotal) {
  int b = blockIdx.x;
  int tid = threadIdx.x;
  if (b < NCB) {
    __shared__ uint hist[NBK];
    for (int i = tid; i < NBK; i += 256) hist[i] = 0;
    __syncthreads();
    int base = b * CHUNK;
    int lim = min(base + CHUNK, E);
    for (int e = base + tid; e < lim; e += 256) atomicAdd(&hist[(uint)dst[e] >> 10], 1u);
    __syncthreads();
    for (int i = tid; i < NBK; i += 256)
      if (hist[i]) atomicAdd(&bcnt[i], hist[i]);
  } else if (b < NCB + NC) {
    int i = (b - NCB) * 256 + tid;
    if (i < n4) {
      float4 v = ((const float4*)x)[i];
      uint2 o;
      o.x = (uint)f32_to_bf16(v.x) | ((uint)f32_to_bf16(v.y) << 16);
      o.y = (uint)f32_to_bf16(v.z) | ((uint)f32_to_bf16(v.w) << 16);
      ((uint2*)xb)[i] = o;
    }
  } else {
    int g = (b - NCB - NC) * 256 + tid;
    if (g < wtotal) {
      const int offs[8] = {0, 8192, 16384, 32768, 49152, 57344, 65536, 73728};
      int s = 0;
#pragma unroll
      for (int i = 1; i < 8; ++i) s += (g >= offs[i]);
      float w0 = w.p[s][g - offs[s]];
      ushort h = f32_to_bf16(w0);
      float rr = w0 - bf16_to_f32(h);
      whi[g] = h;
      wlo[g] = f32_to_bf16(rr);
    }
  }
}

// ---- tiny scan of 98 bucket counts -> bases + cursors; also rp[NN]=E
__global__ void k_bscan(const uint* __restrict__ bcnt, uint* __restrict__ bbase,
                        uint* __restrict__ bcur, int* __restrict__ rp) {
  if (threadIdx.x == 0) {
    uint s = 0;
    for (int i = 0; i < NBK; ++i) {
      uint c = bcnt[i];
      bbase[i] = s;
      bcur[i] = s;
      s += c;
    }
    bbase[NBK] = s;
    rp[NN] = (int)s;
  }
}

// ---- scatter edges into bucket regions as packed (dstLocal<<20 | src)
__global__ void k_bscatter(const int* __restrict__ src, const int* __restrict__ dst,
                           uint* __restrict__ bcur, uint* __restrict__ packed, int E) {
  __shared__ uint hist[NBK], runbase[NBK], cur[NBK];
  int tid = threadIdx.x;
  for (int i = tid; i < NBK; i += 256) hist[i] = 0;
  __syncthreads();
  int base = blockIdx.x * CHUNK;
  int lim = min(base + CHUNK, E);
  for (int e = base + tid; e < lim; e += 256) atomicAdd(&hist[(uint)dst[e] >> 10], 1u);
  __syncthreads();
  for (int i = tid; i < NBK; i += 256) {
    runbase[i] = hist[i] ? atomicAdd(&bcur[i], hist[i]) : 0u;
    cur[i] = 0;
  }
  __syncthreads();
  for (int e = base + tid; e < lim; e += 256) {
    uint d = (uint)dst[e];
    uint s = (uint)src[e];
    uint bk = d >> 10;
    uint p = runbase[bk] + atomicAdd(&cur[bk], 1u);
    packed[p] = ((d & 1023u) << 20) | s;
  }
}

// ---- per-bucket CSR build: LDS hist + scan -> row_ptr + col
__global__ void k_build(const uint* __restrict__ bbase, const uint* __restrict__ packed,
                        int* __restrict__ rp, int* __restrict__ col) {
  __shared__ uint hist[1024];
  __shared__ uint ws[256];
  int b = blockIdx.x;
  int tid = threadIdx.x;
  uint lo = bbase[b], hi = bbase[b + 1];
#pragma unroll
  for (int i = 0; i < 4; ++i) hist[tid + i * 256] = 0;
  __syncthreads();
  for (uint e = lo + tid; e < hi; e += 256) atomicAdd(&hist[packed[e] >> 20], 1u);
  __syncthreads();
  uint v0 = hist[tid * 4], v1 = hist[tid * 4 + 1], v2 = hist[tid * 4 + 2], v3 = hist[tid * 4 + 3];
  ws[tid] = v0 + v1 + v2 + v3;
  __syncthreads();
  for (int off = 1; off < 256; off <<= 1) {
    uint add = (tid >= off) ? ws[tid - off] : 0u;
    __syncthreads();
    ws[tid] += add;
    __syncthreads();
  }
  uint ex = (tid > 0) ? ws[tid - 1] : 0u;
  hist[tid * 4] = ex;
  hist[tid * 4 + 1] = ex + v0;
  hist[tid * 4 + 2] = ex + v0 + v1;
  hist[tid * 4 + 3] = ex + v0 + v1 + v2;
  int nodeBase = b << 10;
#pragma unroll
  for (int i = 0; i < 4; ++i) {
    int node = nodeBase + tid * 4 + i;
    if (node < NN) rp[node] = (int)(lo + hist[tid * 4 + i]);
  }
  __syncthreads();
  for (uint e = lo + tid; e < hi; e += 256) {
    uint pk = packed[e];
    uint p = atomicAdd(&hist[pk >> 20], 1u);
    col[lo + p] = (int)(pk & 0xFFFFFu);
  }
}

// ---------------- mean aggregation: lane-owns-column, no cross-lane reduce ----------------
// F=128: full wave per node, lane owns cols {2l, 2l+1} (one uint per neighbor row).
// F=64: half-wave per node. MODE: 0 = bf16 out; 2 = emb mode (add u, write f32 + bf16).
#define ACC1(vv) { alo += __uint_as_float((vv) << 16); ahi += __uint_as_float((vv) & 0xffff0000u); }

template <int F, int MODE>
__global__ void k_agg(const ushort* __restrict__ x, const int* __restrict__ rp,
                      const int* __restrict__ col, const float* __restrict__ u,
                      float* __restrict__ of, ushort* __restrict__ ob, int n) {
  constexpr int RS = F / 2;  // uints per row
  int wave = (blockIdx.x * blockDim.x + threadIdx.x) >> 6;
  int lane = threadIdx.x & 63;
  int node, l;
  if (F == 128) { node = wave; l = lane; }
  else { node = wave * 2 + (lane >> 5); l = lane & 31; }
  if (node >= n) return;
  int beg = rp[node], end = rp[node + 1];
  int deg = end - beg;
  const uint* __restrict__ xu = (const uint*)x;
  float alo = 0.f, ahi = 0.f;
  int j = beg;
  for (; j + 8 <= end; j += 8) {
    int c0 = col[j], c1 = col[j + 1], c2 = col[j + 2], c3 = col[j + 3];
    int c4 = col[j + 4], c5 = col[j + 5], c6 = col[j + 6], c7 = col[j + 7];
    uint v0 = xu[(size_t)c0 * RS + l];
    uint v1 = xu[(size_t)c1 * RS + l];
    uint v2 = xu[(size_t)c2 * RS + l];
    uint v3 = xu[(size_t)c3 * RS + l];
    uint v4 = xu[(size_t)c4 * RS + l];
    uint v5 = xu[(size_t)c5 * RS + l];
    uint v6 = xu[(size_t)c6 * RS + l];
    uint v7 = xu[(size_t)c7 * RS + l];
    ACC1(v0) ACC1(v1) ACC1(v2) ACC1(v3) ACC1(v4) ACC1(v5) ACC1(v6) ACC1(v7)
  }
  if (j + 4 <= end) {
    int c0 = col[j], c1 = col[j + 1], c2 = col[j + 2], c3 = col[j + 3];
    uint v0 = xu[(size_t)c0 * RS + l];
    uint v1 = xu[(size_t)c1 * RS + l];
    uint v2 = xu[(size_t)c2 * RS + l];
    uint v3 = xu[(size_t)c3 * RS + l];
    ACC1(v0) ACC1(v1) ACC1(v2) ACC1(v3)
    j += 4;
  }
  for (; j < end; ++j) {
    uint v0 = xu[(size_t)col[j] * RS + l];
    ACC1(v0)
  }
  float inv = 1.0f / (float)(deg > 0 ? deg : 1);
  alo *= inv;
  ahi *= inv;
  if (MODE == 0) {
    ((uint*)ob)[(size_t)node * RS + l] = (uint)f32_to_bf16(alo) | ((uint)f32_to_bf16(ahi) << 16);
  } else {
    float2 uv = ((const float2*)u)[(size_t)node * RS + l];
    float e0 = alo + uv.x, e1 = ahi + uv.y;
    ((float2*)of)[(size_t)node * RS + l] = make_float2(e0, e1);
    ((uint*)ob)[(size_t)node * RS + l] = (uint)f32_to_bf16(e0) | ((uint)f32_to_bf16(e1) << 16);
  }
}

// ---------------- MFMA GEMM: out = act(A@Wa^T [+ B@Wb^T] + bias) ----------------
// W split hi/lo (2 MFMAs each). OUTM: 0 = bf16 out, 1 = f32 out,
// 3 = split (H=128): cols 0-63 -> bf16 outb (stride 64), cols 64-127 -> f32 outf + bias.
template <int K, int H, bool RELU, bool DUAL, int OUTM>
__global__ __launch_bounds__(256, 1) void k_gemm(
    const ushort* __restrict__ A, const ushort* __restrict__ Wah, const ushort* __restrict__ Wal,
    const ushort* __restrict__ B, const ushort* __restrict__ Wbh, const ushort* __restrict__ Wbl,
    const float* __restrict__ bias,
    float* __restrict__ outf, ushort* __restrict__ outb, int n) {
  constexpr int BM = 128;
  constexpr int KT = 64;
  constexpr int NKT = K / KT;
  constexpr int MF = (H == 128) ? 4 : 2;
  __shared__ ushort As[BM * KT];
  __shared__ ushort Ws[2][H * KT];

  const int tid = threadIdx.x;
  const int lane = tid & 63;
  const int wid = tid >> 6;
  const int fr = lane & 15;
  const int fq = lane >> 4;
  const int blockRow = blockIdx.x * BM;
  const int rowBase = (H == 128) ? (wid >> 1) * 64 : wid * 32;
  const int colBase = (H == 128) ? (wid & 1) * 64 : 0;

  f32x4 acc[MF][4];
#pragma unroll
  for (int mi = 0; mi < MF; ++mi)
#pragma unroll
    for (int ni = 0; ni < 4; ++ni) acc[mi][ni] = (f32x4){0.f, 0.f, 0.f, 0.f};

#pragma unroll
  for (int phase = 0; phase < (DUAL ? 2 : 1); ++phase) {
    const ushort* __restrict__ Ap = phase ? B : A;
    const ushort* __restrict__ Wph = phase ? Wbh : Wah;
    const ushort* __restrict__ Wpl = phase ? Wbl : Wal;
#pragma unroll
    for (int kt = 0; kt < NKT; ++kt) {
      __syncthreads();
      for (int c = tid; c < BM * 8; c += 256) {
        int r = c >> 3, kc = c & 7;
        int row = blockRow + r;
        uint4 v = make_uint4(0u, 0u, 0u, 0u);
        if (row < n) v = *(const uint4*)(Ap + (size_t)row * K + kt * KT + kc * 8);
        *(uint4*)((char*)As + r * (KT * 2) + ((kc * 16) ^ ((r & 7) << 4))) = v;
      }
      for (int c = tid; c < H * 8; c += 256) {
        int r = c >> 3, kc = c & 7;
        int boff = r * (KT * 2) + ((kc * 16) ^ ((r & 7) << 4));
        *(uint4*)((char*)Ws[0] + boff) = *(const uint4*)(Wph + (size_t)r * K + kt * KT + kc * 8);
        *(uint4*)((char*)Ws[1] + boff) = *(const uint4*)(Wpl + (size_t)r * K + kt * KT + kc * 8);
      }
      __syncthreads();
#pragma unroll
      for (int ks = 0; ks < 2; ++ks) {
        const int kb = ks * 64 + fq * 16;
        s16x8 af[MF], whf[4], wlf[4];
#pragma unroll
        for (int mi = 0; mi < MF; ++mi) {
          int r = rowBase + mi * 16 + fr;
          af[mi] = *(const s16x8*)((const char*)As + r * (KT * 2) + (kb ^ ((r & 7) << 4)));
        }
#pragma unroll
        for (int ni = 0; ni < 4; ++ni) {
          int r = colBase + ni * 16 + fr;
          int boff = r * (KT * 2) + (kb ^ ((r & 7) << 4));
          whf[ni] = *(const s16x8*)((const char*)Ws[0] + boff);
          wlf[ni] = *(const s16x8*)((const char*)Ws[1] + boff);
        }
#pragma unroll
        for (int mi = 0; mi < MF; ++mi)
#pragma unroll
          for (int ni = 0; ni < 4; ++ni) {
            acc[mi][ni] = __builtin_amdgcn_mfma_f32_16x16x32_bf16(af[mi], wlf[ni], acc[mi][ni], 0, 0, 0);
            acc[mi][ni] = __builtin_amdgcn_mfma_f32_16x16x32_bf16(af[mi], whf[ni], acc[mi][ni], 0, 0, 0);
          }
      }
    }
  }
#pragma unroll
  for (int mi = 0; mi < MF; ++mi) {
#pragma unroll
    for (int ni = 0; ni < 4; ++ni) {
#pragma unroll
      for (int r = 0; r < 4; ++r) {
        int row = blockRow + rowBase + mi * 16 + fq * 4 + r;
        int colI = colBase + ni * 16 + fr;
        if (row < n) {
          float v = acc[mi][ni][r];
          if (OUTM == 3) {
            if (colI < 64)
              outb[(size_t)row * 64 + colI] = f32_to_bf16(v);
            else
              outf[(size_t)row * 64 + (colI - 64)] = v + bias[colI - 64];
          } else {
            if (bias) v += bias[colI];
            if (RELU) v = fmaxf(v, 0.f);
            if (OUTM == 1) outf[(size_t)row * H + colI] = v;
            else outb[(size_t)row * H + colI] = f32_to_bf16(v);
          }
        }
      }
    }
  }
}

// ---------------- edge dot: half-wave per edge ----------------
__global__ void k_dot(const float* __restrict__ emb, const int* __restrict__ ea,
                      const int* __restrict__ eb, float* __restrict__ out, int ne) {
  int hw = (blockIdx.x * blockDim.x + threadIdx.x) >> 5;
  int l = threadIdx.x & 31;
  if (hw >= ne) return;
  float2 a = ((const float2*)(emb + (size_t)ea[hw] * 64))[l];
  float2 b = ((const float2*)(emb + (size_t)eb[hw] * 64))[l];
  float v = a.x * b.x + a.y * b.y;
#pragma unroll
  for (int off = 16; off; off >>= 1) v += __shfl_xor(v, off, 64);
  if (l == 0) out[hw] = v;
}

extern "C" void kernel_launch(void* const* d_in, const int* in_sizes, int n_in,
                              void* d_out, int out_size, void* d_ws, size_t ws_size,
                              hipStream_t stream) {
  const float* x = (const float*)d_in[0];
  const int* ei = (const int*)d_in[1];
  const int* es = (const int*)d_in[2];
  const float* b0 = (const float*)d_in[5];
  const float* b1 = (const float*)d_in[8];
  const float* b2 = (const float*)d_in[11];
  const float* bd1 = (const float*)d_in[13];
  const float* bd2 = (const float*)d_in[15];

  const int E = in_sizes[1] / 2;
  const int ES = in_sizes[2] / 2;
  const int* srcv = ei;
  const int* dstv = ei + E;
  const int* ea = es;
  const int* eb = es + ES;

  char* wp = (char*)d_ws;
  auto alloc = [&](size_t bytes) {
    char* p = wp;
    wp += (bytes + 511) & ~(size_t)511;
    return p;
  };
  int* row_ptr = (int*)alloc((NN + 1) * sizeof(int));
  uint* bcnt = (uint*)alloc(NBK * sizeof(uint));
  uint* bbase = (uint*)alloc((NBK + 1) * sizeof(uint));
  uint* bcur = (uint*)alloc(NBK * sizeof(uint));
  uint* packed = (uint*)alloc((size_t)E * sizeof(uint));
  int* colv = (int*)alloc((size_t)E * sizeof(int));
  ushort* xb = (ushort*)alloc((size_t)NN * 64 * 2);
  ushort* aggb = (ushort*)alloc((size_t)NN * 128 * 2);
  ushort* h1b = (ushort*)alloc((size_t)NN * 128 * 2);
  ushort* h2b = (ushort*)alloc((size_t)NN * 128 * 2);
  float* uf = (float*)alloc((size_t)NN * 64 * 4);
  ushort* embb = (ushort*)alloc((size_t)NN * 64 * 2);
  ushort* Whb = (ushort*)alloc(81920 * 2);
  ushort* Wlb = (ushort*)alloc(81920 * 2);

  const int WO0 = 0, WO1 = 8192, WO2 = 16384, WO3 = 32768, WO4 = 49152,
            WO6 = 65536, WO7 = 73728;  // WO4: Wl2|Wr2 contiguous (H=128)

  float* out_emb = (float*)d_out;
  float* out_rec = out_emb + (size_t)NN * 64;
  float* out_sc = out_rec + (size_t)NN * 64;

  hipMemsetAsync(bcnt, 0, NBK * sizeof(uint), stream);

  P8 wptrs;
  wptrs.p[0] = (const float*)d_in[3];  wptrs.p[1] = (const float*)d_in[4];
  wptrs.p[2] = (const float*)d_in[6];  wptrs.p[3] = (const float*)d_in[7];
  wptrs.p[4] = (const float*)d_in[9];  wptrs.p[5] = (const float*)d_in[10];
  wptrs.p[6] = (const float*)d_in[12]; wptrs.p[7] = (const float*)d_in[14];

  const int NCB = (E + CHUNK - 1) / CHUNK;
  const int n4 = NN * 64 / 4;
  const int NC = (n4 + 255) / 256;
  const int NS = (81920 + 255) / 256;
  k_prep<<<NCB + NC + NS, 256, 0, stream>>>(dstv, bcnt, E, NCB, x, xb, n4, NC,
                                            wptrs, Whb, Wlb, 81920);
  k_bscan<<<1, 64, 0, stream>>>(bcnt, bbase, bcur, row_ptr);
  k_bscatter<<<NCB, 256, 0, stream>>>(srcv, dstv, bcur, packed, E);
  k_build<<<NBK, 256, 0, stream>>>(bbase, packed, row_ptr, colv);

  const int g64 = (NN + 7) / 8;    // half-wave per node
  const int g128a = (NN + 3) / 4;  // wave per node
  dim3 gg((NN + 127) / 128);

  // layer 0
  k_agg<64, 0><<<g64, 256, 0, stream>>>(xb, row_ptr, colv, nullptr, nullptr, aggb, NN);
  k_gemm<64, 128, true, true, 0><<<gg, 256, 0, stream>>>(
      aggb, Whb + WO0, Wlb + WO0, xb, Whb + WO1, Wlb + WO1, b0, nullptr, h1b, NN);
  // layer 1
  k_agg<128, 0><<<g128a, 256, 0, stream>>>(h1b, row_ptr, colv, nullptr, nullptr, aggb, NN);
  k_gemm<128, 128, true, true, 0><<<gg, 256, 0, stream>>>(
      aggb, Whb + WO2, Wlb + WO2, h1b, Whb + WO3, Wlb + WO3, b1, nullptr, h2b, NN);
  // layer 2 fused: one pass over h2 -> t = h2@Wl2^T (bf16, aggb) and u = h2@Wr2^T + b2 (f32)
  k_gemm<128, 128, false, false, 3><<<gg, 256, 0, stream>>>(
      h2b, Whb + WO4, Wlb + WO4, nullptr, nullptr, nullptr, b2, uf, aggb, NN);
  // emb = mean(t) + u  (writes f32 out_emb + bf16 embb)
  k_agg<64, 2><<<g64, 256, 0, stream>>>(aggb, row_ptr, colv, uf, out_emb, embb, NN);
  // decoder
  k_gemm<64, 128, true, false, 0><<<gg, 256, 0, stream>>>(
      embb, Whb + WO6, Wlb + WO6, nullptr, nullptr, nullptr, bd1, nullptr, h1b, NN);
  k_gemm<128, 64, false, false, 1><<<gg, 256, 0, stream>>>(
      h1b, Whb + WO7, Wlb + WO7, nullptr, nullptr, nullptr, bd2, out_rec, nullptr, NN);
  // edge scores
  k_dot<<<(ES + 7) / 8, 256, 0, stream>>>(out_emb, ea, eb, out_sc, ES);
}

// Round 6
// 366.618 us; speedup vs baseline: 2.9715x; 1.1033x over previous
//
#include <hip/hip_runtime.h>

#define NN 100000
#define NBK 98      // node buckets: bucket = dst >> 10 (1024 nodes each)
#define CHUNK 8192  // edges per block in bucket passes
typedef unsigned int uint;
typedef unsigned short ushort;

using f32x4 = __attribute__((ext_vector_type(4))) float;
using s16x8 = __attribute__((ext_vector_type(8))) short;

__device__ inline ushort f32_to_bf16(float f) {
  uint u = __float_as_uint(f);
  uint r = (u + 0x7FFFu + ((u >> 16) & 1u)) >> 16;
  return (ushort)r;
}
__device__ inline float bf16_to_f32(ushort h) {
  return __uint_as_float(((uint)h) << 16);
}

typedef __attribute__((address_space(1))) const unsigned int gas_u32;
typedef __attribute__((address_space(3))) unsigned int las_u32;
__device__ __forceinline__ void gld_lds16(const void* gp, void* lp) {
  __builtin_amdgcn_global_load_lds((gas_u32*)gp, (las_u32*)lp, 16, 0, 0);
}

struct P8 { const float* p[8]; };

// ---- fused prep: bucket-count (LDS hist) + x->bf16 cvt + weight bf16 cvt
__global__ void k_prep(const int* __restrict__ dst, uint* __restrict__ bcnt, int E, int NCB,
                       const float* __restrict__ x, ushort* __restrict__ xb, int n4, int NC,
                       P8 w, ushort* __restrict__ whi, int wtotal) {
  int b = blockIdx.x;
  int tid = threadIdx.x;
  if (b < NCB) {
    __shared__ uint hist[NBK];
    for (int i = tid; i < NBK; i += 256) hist[i] = 0;
    __syncthreads();
    int base = b * CHUNK;
    int lim = min(base + CHUNK, E);
    for (int e = base + tid; e < lim; e += 256) atomicAdd(&hist[(uint)dst[e] >> 10], 1u);
    __syncthreads();
    for (int i = tid; i < NBK; i += 256)
      if (hist[i]) atomicAdd(&bcnt[i], hist[i]);
  } else if (b < NCB + NC) {
    int i = (b - NCB) * 256 + tid;
    if (i < n4) {
      float4 v = ((const float4*)x)[i];
      uint2 o;
      o.x = (uint)f32_to_bf16(v.x) | ((uint)f32_to_bf16(v.y) << 16);
      o.y = (uint)f32_to_bf16(v.z) | ((uint)f32_to_bf16(v.w) << 16);
      ((uint2*)xb)[i] = o;
    }
  } else {
    int g = (b - NCB - NC) * 256 + tid;
    if (g < wtotal) {
      const int offs[8] = {0, 8192, 16384, 32768, 49152, 57344, 65536, 73728};
      int s = 0;
#pragma unroll
      for (int i = 1; i < 8; ++i) s += (g >= offs[i]);
      whi[g] = f32_to_bf16(w.p[s][g - offs[s]]);
    }
  }
}

// ---- tiny scan of 98 bucket counts -> bases + cursors; also rp[NN]=E
__global__ void k_bscan(const uint* __restrict__ bcnt, uint* __restrict__ bbase,
                        uint* __restrict__ bcur, int* __restrict__ rp) {
  if (threadIdx.x == 0) {
    uint s = 0;
    for (int i = 0; i < NBK; ++i) {
      uint c = bcnt[i];
      bbase[i] = s;
      bcur[i] = s;
      s += c;
    }
    bbase[NBK] = s;
    rp[NN] = (int)s;
  }
}

// ---- scatter edges into bucket regions as packed (dstLocal<<20 | src)
__global__ void k_bscatter(const int* __restrict__ src, const int* __restrict__ dst,
                           uint* __restrict__ bcur, uint* __restrict__ packed, int E) {
  __shared__ uint hist[NBK], runbase[NBK], cur[NBK];
  int tid = threadIdx.x;
  for (int i = tid; i < NBK; i += 256) hist[i] = 0;
  __syncthreads();
  int base = blockIdx.x * CHUNK;
  int lim = min(base + CHUNK, E);
  for (int e = base + tid; e < lim; e += 256) atomicAdd(&hist[(uint)dst[e] >> 10], 1u);
  __syncthreads();
  for (int i = tid; i < NBK; i += 256) {
    runbase[i] = hist[i] ? atomicAdd(&bcur[i], hist[i]) : 0u;
    cur[i] = 0;
  }
  __syncthreads();
  for (int e = base + tid; e < lim; e += 256) {
    uint d = (uint)dst[e];
    uint s = (uint)src[e];
    uint bk = d >> 10;
    uint p = runbase[bk] + atomicAdd(&cur[bk], 1u);
    packed[p] = ((d & 1023u) << 20) | s;
  }
}

// ---- per-bucket CSR build: LDS hist + scan -> row_ptr + col
__global__ void k_build(const uint* __restrict__ bbase, const uint* __restrict__ packed,
                        int* __restrict__ rp, int* __restrict__ col) {
  __shared__ uint hist[1024];
  __shared__ uint ws[256];
  int b = blockIdx.x;
  int tid = threadIdx.x;
  uint lo = bbase[b], hi = bbase[b + 1];
#pragma unroll
  for (int i = 0; i < 4; ++i) hist[tid + i * 256] = 0;
  __syncthreads();
  for (uint e = lo + tid; e < hi; e += 256) atomicAdd(&hist[packed[e] >> 20], 1u);
  __syncthreads();
  uint v0 = hist[tid * 4], v1 = hist[tid * 4 + 1], v2 = hist[tid * 4 + 2], v3 = hist[tid * 4 + 3];
  ws[tid] = v0 + v1 + v2 + v3;
  __syncthreads();
  for (int off = 1; off < 256; off <<= 1) {
    uint add = (tid >= off) ? ws[tid - off] : 0u;
    __syncthreads();
    ws[tid] += add;
    __syncthreads();
  }
  uint ex = (tid > 0) ? ws[tid - 1] : 0u;
  hist[tid * 4] = ex;
  hist[tid * 4 + 1] = ex + v0;
  hist[tid * 4 + 2] = ex + v0 + v1;
  hist[tid * 4 + 3] = ex + v0 + v1 + v2;
  int nodeBase = b << 10;
#pragma unroll
  for (int i = 0; i < 4; ++i) {
    int node = nodeBase + tid * 4 + i;
    if (node < NN) rp[node] = (int)(lo + hist[tid * 4 + i]);
  }
  __syncthreads();
  for (uint e = lo + tid; e < hi; e += 256) {
    uint pk = packed[e];
    uint p = atomicAdd(&hist[pk >> 20], 1u);
    col[lo + p] = (int)(pk & 0xFFFFFu);
  }
}

// ---------------- mean aggregation: lane-owns-column, no cross-lane reduce ----------------
#define ACC1(vv) { alo += __uint_as_float((vv) << 16); ahi += __uint_as_float((vv) & 0xffff0000u); }

template <int F, int MODE>
__global__ void k_agg(const ushort* __restrict__ x, const int* __restrict__ rp,
                      const int* __restrict__ col, const float* __restrict__ u,
                      float* __restrict__ of, ushort* __restrict__ ob, int n) {
  constexpr int RS = F / 2;  // uints per row
  int wave = (blockIdx.x * blockDim.x + threadIdx.x) >> 6;
  int lane = threadIdx.x & 63;
  int node, l;
  if (F == 128) { node = wave; l = lane; }
  else { node = wave * 2 + (lane >> 5); l = lane & 31; }
  if (node >= n) return;
  int beg = rp[node], end = rp[node + 1];
  int deg = end - beg;
  const uint* __restrict__ xu = (const uint*)x;
  float alo = 0.f, ahi = 0.f;
  int j = beg;
  for (; j + 8 <= end; j += 8) {
    int c0 = col[j], c1 = col[j + 1], c2 = col[j + 2], c3 = col[j + 3];
    int c4 = col[j + 4], c5 = col[j + 5], c6 = col[j + 6], c7 = col[j + 7];
    uint v0 = xu[(size_t)c0 * RS + l];
    uint v1 = xu[(size_t)c1 * RS + l];
    uint v2 = xu[(size_t)c2 * RS + l];
    uint v3 = xu[(size_t)c3 * RS + l];
    uint v4 = xu[(size_t)c4 * RS + l];
    uint v5 = xu[(size_t)c5 * RS + l];
    uint v6 = xu[(size_t)c6 * RS + l];
    uint v7 = xu[(size_t)c7 * RS + l];
    ACC1(v0) ACC1(v1) ACC1(v2) ACC1(v3) ACC1(v4) ACC1(v5) ACC1(v6) ACC1(v7)
  }
  if (j + 4 <= end) {
    int c0 = col[j], c1 = col[j + 1], c2 = col[j + 2], c3 = col[j + 3];
    uint v0 = xu[(size_t)c0 * RS + l];
    uint v1 = xu[(size_t)c1 * RS + l];
    uint v2 = xu[(size_t)c2 * RS + l];
    uint v3 = xu[(size_t)c3 * RS + l];
    ACC1(v0) ACC1(v1) ACC1(v2) ACC1(v3)
    j += 4;
  }
  for (; j < end; ++j) {
    uint v0 = xu[(size_t)col[j] * RS + l];
    ACC1(v0)
  }
  float inv = 1.0f / (float)(deg > 0 ? deg : 1);
  alo *= inv;
  ahi *= inv;
  if (MODE == 0) {
    ((uint*)ob)[(size_t)node * RS + l] = (uint)f32_to_bf16(alo) | ((uint)f32_to_bf16(ahi) << 16);
  } else {
    float2 uv = ((const float2*)u)[(size_t)node * RS + l];
    float e0 = alo + uv.x, e1 = ahi + uv.y;
    ((float2*)of)[(size_t)node * RS + l] = make_float2(e0, e1);
    ((uint*)ob)[(size_t)node * RS + l] = (uint)f32_to_bf16(e0) | ((uint)f32_to_bf16(e1) << 16);
  }
}

// ---------------- MFMA GEMM: out = act(A@Wa^T [+ B@Wb^T] + bias) ----------------
// Single bf16 weight plane. A,B,W bf16. Staging via global_load_lds (swizzled source).
// OUTM: 0 = bf16 out, 1 = f32 out,
// 3 = split (H=128): cols 0-63 -> bf16 outb (stride 64), cols 64-127 -> f32 outf + bias.
template <int K, int H, bool RELU, bool DUAL, int OUTM>
__global__ __launch_bounds__(256) void k_gemm(
    const ushort* __restrict__ A, const ushort* __restrict__ Wa,
    const ushort* __restrict__ B, const ushort* __restrict__ Wb,
    const float* __restrict__ bias,
    float* __restrict__ outf, ushort* __restrict__ outb, int n) {
  constexpr int BM = 128;
  constexpr int KT = 64;
  constexpr int NKT = K / KT;
  constexpr int MF = (H == 128) ? 4 : 2;
  constexpr int WCH = H / 32;  // W chunks (8 rows, 1KB) per wave
  __shared__ ushort As[BM * KT];  // 16KB, XOR-swizzled
  __shared__ ushort Ws[H * KT];   // 16/8KB

  const int tid = threadIdx.x;
  const int lane = tid & 63;
  const int wid = tid >> 6;
  const int fr = lane & 15;
  const int fq = lane >> 4;
  const int blockRow = blockIdx.x * BM;
  const int rowBase = (H == 128) ? (wid >> 1) * 64 : wid * 32;
  const int colBase = (H == 128) ? (wid & 1) * 64 : 0;
  // async-staging lane constants: chunk = 8 rows; lane covers (row l>>3, slot (l&7)^(l>>3))
  const int srow = lane >> 3;
  const int sslot = (lane & 7) ^ srow;
  const bool fullTile = (blockRow + BM <= n);

  f32x4 acc[MF][4];
#pragma unroll
  for (int mi = 0; mi < MF; ++mi)
#pragma unroll
    for (int ni = 0; ni < 4; ++ni) acc[mi][ni] = (f32x4){0.f, 0.f, 0.f, 0.f};

#pragma unroll
  for (int phase = 0; phase < (DUAL ? 2 : 1); ++phase) {
    const ushort* __restrict__ Ap = phase ? B : A;
    const ushort* __restrict__ Wp = phase ? Wb : Wa;
#pragma unroll
    for (int kt = 0; kt < NKT; ++kt) {
      const int ktb = kt * KT;
      __syncthreads();
      if (fullTile) {
        // A tile: 16 chunks of 8 rows, 4 per wave (async, swizzle folded into source addr)
#pragma unroll
        for (int i = 0; i < 4; ++i) {
          int r0 = (wid + i * 4) * 8;
          gld_lds16(Ap + (size_t)(blockRow + r0 + srow) * K + ktb + sslot * 8,
                    (char*)As + r0 * 128);
        }
#pragma unroll
        for (int i = 0; i < WCH; ++i) {
          int r0 = (wid + i * 4) * 8;
          if (WCH >= 4 || wid + i * 4 < WCH * 4)
            gld_lds16(Wp + (size_t)(r0 + srow) * K + ktb + sslot * 8,
                      (char*)Ws + r0 * 128);
        }
      } else {
        for (int c = tid; c < BM * 8; c += 256) {
          int r = c >> 3, kc = c & 7;
          int row = blockRow + r;
          uint4 v = make_uint4(0u, 0u, 0u, 0u);
          if (row < n) v = *(const uint4*)(Ap + (size_t)row * K + ktb + kc * 8);
          *(uint4*)((char*)As + r * 128 + ((kc * 16) ^ ((r & 7) << 4))) = v;
        }
        for (int c = tid; c < H * 8; c += 256) {
          int r = c >> 3, kc = c & 7;
          *(uint4*)((char*)Ws + r * 128 + ((kc * 16) ^ ((r & 7) << 4))) =
              *(const uint4*)(Wp + (size_t)r * K + ktb + kc * 8);
        }
      }
      __syncthreads();
#pragma unroll
      for (int ks = 0; ks < 2; ++ks) {
        const int kb = ks * 64 + fq * 16;
        s16x8 af[MF], wf[4];
#pragma unroll
        for (int mi = 0; mi < MF; ++mi) {
          int r = rowBase + mi * 16 + fr;
          af[mi] = *(const s16x8*)((const char*)As + r * 128 + (kb ^ ((r & 7) << 4)));
        }
#pragma unroll
        for (int ni = 0; ni < 4; ++ni) {
          int r = colBase + ni * 16 + fr;
          wf[ni] = *(const s16x8*)((const char*)Ws + r * 128 + (kb ^ ((r & 7) << 4)));
        }
#pragma unroll
        for (int mi = 0; mi < MF; ++mi)
#pragma unroll
          for (int ni = 0; ni < 4; ++ni)
            acc[mi][ni] = __builtin_amdgcn_mfma_f32_16x16x32_bf16(af[mi], wf[ni], acc[mi][ni], 0, 0, 0);
      }
    }
  }
#pragma unroll
  for (int mi = 0; mi < MF; ++mi) {
#pragma unroll
    for (int ni = 0; ni < 4; ++ni) {
#pragma unroll
      for (int r = 0; r < 4; ++r) {
        int row = blockRow + rowBase + mi * 16 + fq * 4 + r;
        int colI = colBase + ni * 16 + fr;
        if (row < n) {
          float v = acc[mi][ni][r];
          if (OUTM == 3) {
            if (colI < 64)
              outb[(size_t)row * 64 + colI] = f32_to_bf16(v);
            else
              outf[(size_t)row * 64 + (colI - 64)] = v + bias[colI - 64];
          } else {
            if (bias) v += bias[colI];
            if (RELU) v = fmaxf(v, 0.f);
            if (OUTM == 1) outf[(size_t)row * H + colI] = v;
            else outb[(size_t)row * H + colI] = f32_to_bf16(v);
          }
        }
      }
    }
  }
}

// ---------------- edge dot: half-wave per edge ----------------
__global__ void k_dot(const float* __restrict__ emb, const int* __restrict__ ea,
                      const int* __restrict__ eb, float* __restrict__ out, int ne) {
  int hw = (blockIdx.x * blockDim.x + threadIdx.x) >> 5;
  int l = threadIdx.x & 31;
  if (hw >= ne) return;
  float2 a = ((const float2*)(emb + (size_t)ea[hw] * 64))[l];
  float2 b = ((const float2*)(emb + (size_t)eb[hw] * 64))[l];
  float v = a.x * b.x + a.y * b.y;
#pragma unroll
  for (int off = 16; off; off >>= 1) v += __shfl_xor(v, off, 64);
  if (l == 0) out[hw] = v;
}

extern "C" void kernel_launch(void* const* d_in, const int* in_sizes, int n_in,
                              void* d_out, int out_size, void* d_ws, size_t ws_size,
                              hipStream_t stream) {
  const float* x = (const float*)d_in[0];
  const int* ei = (const int*)d_in[1];
  const int* es = (const int*)d_in[2];
  const float* b0 = (const float*)d_in[5];
  const float* b1 = (const float*)d_in[8];
  const float* b2 = (const float*)d_in[11];
  const float* bd1 = (const float*)d_in[13];
  const float* bd2 = (const float*)d_in[15];

  const int E = in_sizes[1] / 2;
  const int ES = in_sizes[2] / 2;
  const int* srcv = ei;
  const int* dstv = ei + E;
  const int* ea = es;
  const int* eb = es + ES;

  char* wp = (char*)d_ws;
  auto alloc = [&](size_t bytes) {
    char* p = wp;
    wp += (bytes + 511) & ~(size_t)511;
    return p;
  };
  int* row_ptr = (int*)alloc((NN + 1) * sizeof(int));
  uint* bcnt = (uint*)alloc(NBK * sizeof(uint));
  uint* bbase = (uint*)alloc((NBK + 1) * sizeof(uint));
  uint* bcur = (uint*)alloc(NBK * sizeof(uint));
  uint* packed = (uint*)alloc((size_t)E * sizeof(uint));
  int* colv = (int*)alloc((size_t)E * sizeof(int));
  ushort* xb = (ushort*)alloc((size_t)NN * 64 * 2);
  ushort* aggb = (ushort*)alloc((size_t)NN * 128 * 2);
  ushort* h1b = (ushort*)alloc((size_t)NN * 128 * 2);
  ushort* h2b = (ushort*)alloc((size_t)NN * 128 * 2);
  float* uf = (float*)alloc((size_t)NN * 64 * 4);
  ushort* embb = (ushort*)alloc((size_t)NN * 64 * 2);
  ushort* Whb = (ushort*)alloc(81920 * 2);

  const int WO0 = 0, WO1 = 8192, WO2 = 16384, WO3 = 32768, WO4 = 49152,
            WO6 = 65536, WO7 = 73728;  // WO4: Wl2|Wr2 contiguous (H=128)

  float* out_emb = (float*)d_out;
  float* out_rec = out_emb + (size_t)NN * 64;
  float* out_sc = out_rec + (size_t)NN * 64;

  hipMemsetAsync(bcnt, 0, NBK * sizeof(uint), stream);

  P8 wptrs;
  wptrs.p[0] = (const float*)d_in[3];  wptrs.p[1] = (const float*)d_in[4];
  wptrs.p[2] = (const float*)d_in[6];  wptrs.p[3] = (const float*)d_in[7];
  wptrs.p[4] = (const float*)d_in[9];  wptrs.p[5] = (const float*)d_in[10];
  wptrs.p[6] = (const float*)d_in[12]; wptrs.p[7] = (const float*)d_in[14];

  const int NCB = (E + CHUNK - 1) / CHUNK;
  const int n4 = NN * 64 / 4;
  const int NC = (n4 + 255) / 256;
  const int NS = (81920 + 255) / 256;
  k_prep<<<NCB + NC + NS, 256, 0, stream>>>(dstv, bcnt, E, NCB, x, xb, n4, NC,
                                            wptrs, Whb, 81920);
  k_bscan<<<1, 64, 0, stream>>>(bcnt, bbase, bcur, row_ptr);
  k_bscatter<<<NCB, 256, 0, stream>>>(srcv, dstv, bcur, packed, E);
  k_build<<<NBK, 256, 0, stream>>>(bbase, packed, row_ptr, colv);

  const int g64 = (NN + 7) / 8;    // half-wave per node
  const int g128a = (NN + 3) / 4;  // wave per node
  dim3 gg((NN + 127) / 128);

  // layer 0
  k_agg<64, 0><<<g64, 256, 0, stream>>>(xb, row_ptr, colv, nullptr, nullptr, aggb, NN);
  k_gemm<64, 128, true, true, 0><<<gg, 256, 0, stream>>>(
      aggb, Whb + WO0, xb, Whb + WO1, b0, nullptr, h1b, NN);
  // layer 1
  k_agg<128, 0><<<g128a, 256, 0, stream>>>(h1b, row_ptr, colv, nullptr, nullptr, aggb, NN);
  k_gemm<128, 128, true, true, 0><<<gg, 256, 0, stream>>>(
      aggb, Whb + WO2, h1b, Whb + WO3, b1, nullptr, h2b, NN);
  // layer 2 fused: one pass over h2 -> t = h2@Wl2^T (bf16, aggb) and u = h2@Wr2^T + b2 (f32)
  k_gemm<128, 128, false, false, 3><<<gg, 256, 0, stream>>>(
      h2b, Whb + WO4, nullptr, nullptr, b2, uf, aggb, NN);
  // emb = mean(t) + u  (writes f32 out_emb + bf16 embb)
  k_agg<64, 2><<<g64, 256, 0, stream>>>(aggb, row_ptr, colv, uf, out_emb, embb, NN);
  // decoder
  k_gemm<64, 128, true, false, 0><<<gg, 256, 0, stream>>>(
      embb, Whb + WO6, nullptr, nullptr, bd1, nullptr, h1b, NN);
  k_gemm<128, 64, false, false, 1><<<gg, 256, 0, stream>>>(
      h1b, Whb + WO7, nullptr, nullptr, bd2, out_rec, nullptr, NN);
  // edge scores
  k_dot<<<(ES + 7) / 8, 256, 0, stream>>>(out_emb, ea, eb, out_sc, ES);
}